// Round 13
// baseline (607.786 us; speedup 1.0000x reference)
//
#include <hip/hip_runtime.h>

// HSMM forward, scaled linear recurrence.
// R13 = R12's counted-vmcnt LDS-ring H staging with the two staging hazards
// fixed: (1) STAGE uses 6x size-4 global_load_lds (lane-stride semantics
// HW-proven; size-12's LDS stride was unverified and is the prime NaN
// suspect); (2) tail clamps to idempotent re-stage of slab 511 so the
// counted vmcnt(12) always pins the slab needed two regions later.
// Recurrence math bit-identical to R11 (passed, absmax 0).
// ws: H2 u32[16][512][256][6] (48MiB); part f32[11][64][256]; Bimg bf16 128KB;
//     Pexp f32[256][256]; logZ[11][256]; lseZ[256]; lt[11][256]; ltmz[11][256].

#define VV 50000
#define ZB 256
#define LB 11
#define BB 16
#define TB 512
#define NCHUNK 64
#define CROWS 782  // ceil(VV/NCHUNK)

typedef float v2f __attribute__((ext_vector_type(2)));
typedef float v4f __attribute__((ext_vector_type(4)));
typedef short bs8 __attribute__((ext_vector_type(8)));
typedef __attribute__((address_space(3))) void lds_vt;
typedef const __attribute__((address_space(1))) void gm_vt;

static __device__ __forceinline__ float bf16u_to_f(unsigned short u) {
  return __uint_as_float(((unsigned int)u) << 16);
}
static __device__ __forceinline__ unsigned short f_to_bf16u(float f) {
  unsigned int b = __float_as_uint(f);
  b += 0x7FFFu + ((b >> 16) & 1u);
  return (unsigned short)(b >> 16);
}
static __device__ __forceinline__ v2f fma2(v2f a, v2f b, v2f c) {
  return __builtin_elementwise_fma(a, b, c);
}
template <int CTRL>
static __device__ __forceinline__ float dppmax(float x) {
  const int y = __builtin_amdgcn_update_dpp(0, __float_as_int(x), CTRL, 0xF, 0xF, true);
  return fmaxf(x, __int_as_float(y));
}
static __device__ __forceinline__ float rowmax16(float x) {
  x = dppmax<0xB1>(x);   // quad_perm [1,0,3,2]
  x = dppmax<0x4E>(x);   // quad_perm [2,3,0,1]
  x = dppmax<0x124>(x);  // row_ror:4
  x = dppmax<0x128>(x);  // row_ror:8
  return x;
}

#define BAR() do { asm volatile("s_waitcnt lgkmcnt(0)" ::: "memory"); \
                   __builtin_amdgcn_s_barrier();                      \
                   asm volatile("" ::: "memory"); } while (0)

// ---- K1: per-chunk sum of exp(emb) over v (no-max: emb ~ N(0,1), safe in f32)
__global__ void k1_sumexp(const float* __restrict__ emb, float* __restrict__ part) {
  const int l = blockIdx.x / NCHUNK;
  const int c = blockIdx.x % NCHUNK;
  const int t = threadIdx.x;           // 512 threads
  const int zi = (t & 63) * 4;
  const int ro = t >> 6;               // 0..7
  const int v0 = c * CROWS;
  const int v1 = (v0 + CROWS < VV) ? (v0 + CROWS) : VV;
  const float* base = emb + (size_t)l * VV * ZB;
  float a0 = 0.f, a1 = 0.f, a2 = 0.f, a3 = 0.f;
  int v = v0 + ro;
  for (; v + 24 < v1; v += 32) {
    float4 x0 = *(const float4*)(base + (size_t)(v)*ZB + zi);
    float4 x1 = *(const float4*)(base + (size_t)(v + 8) * ZB + zi);
    float4 x2 = *(const float4*)(base + (size_t)(v + 16) * ZB + zi);
    float4 x3 = *(const float4*)(base + (size_t)(v + 24) * ZB + zi);
    a0 += __expf(x0.x) + __expf(x1.x) + __expf(x2.x) + __expf(x3.x);
    a1 += __expf(x0.y) + __expf(x1.y) + __expf(x2.y) + __expf(x3.y);
    a2 += __expf(x0.z) + __expf(x1.z) + __expf(x2.z) + __expf(x3.z);
    a3 += __expf(x0.w) + __expf(x1.w) + __expf(x2.w) + __expf(x3.w);
  }
  for (; v < v1; v += 8) {
    float4 x0 = *(const float4*)(base + (size_t)v * ZB + zi);
    a0 += __expf(x0.x); a1 += __expf(x0.y); a2 += __expf(x0.z); a3 += __expf(x0.w);
  }
  __shared__ float red[8][ZB];
  red[ro][zi] = a0; red[ro][zi + 1] = a1; red[ro][zi + 2] = a2; red[ro][zi + 3] = a3;
  __syncthreads();
  if (t < ZB) {
    float s = 0.f;
#pragma unroll
    for (int r = 0; r < 8; ++r) s += red[r][t];
    part[((size_t)l * NCHUNK + c) * ZB + t] = s;
  }
}

// ---- K2: combine partials -> logZ; lse over l of l_per_z; Pexp rows + Bimg
__global__ void k2_combine(const float* __restrict__ part, const float* __restrict__ zpz,
                           const float* __restrict__ lpz, float* __restrict__ logZ,
                           float* __restrict__ lseZ, float* __restrict__ Pexp,
                           unsigned short* __restrict__ Bimg) {
  const int bid = blockIdx.x;
  const int t = threadIdx.x;  // 256
  if (bid < LB) {
    float s = 0.f;
    for (int c = 0; c < NCHUNK; ++c) s += part[((size_t)bid * NCHUNK + c) * ZB + t];
    logZ[bid * ZB + t] = __logf(s);
  } else if (bid == LB) {
    float lv[LB]; float m = -1e30f;
#pragma unroll
    for (int l = 0; l < LB; ++l) { lv[l] = lpz[t * LB + l]; m = fmaxf(m, lv[l]); }
    float s = 0.f;
#pragma unroll
    for (int l = 0; l < LB; ++l) s += __expf(lv[l] - m);
    lseZ[t] = m + __logf(s);
  } else {
    const int r = bid - (LB + 1);  // z (row of P)
    const float x = zpz[r * ZB + t];
    __shared__ float sA[4], sB[4];
    float m = x;
#pragma unroll
    for (int off = 32; off >= 1; off >>= 1) m = fmaxf(m, __shfl_xor(m, off, 64));
    if ((t & 63) == 0) sA[t >> 6] = m;
    __syncthreads();
    m = fmaxf(fmaxf(sA[0], sA[1]), fmaxf(sA[2], sA[3]));
    const float e = __expf(x - m);
    float s = e;
#pragma unroll
    for (int off = 32; off >= 1; off >>= 1) s += __shfl_xor(s, off, 64);
    if ((t & 63) == 0) sB[t >> 6] = s;
    __syncthreads();
    const float tot = sB[0] + sB[1] + sB[2] + sB[3];
    const float P = e / tot;
    Pexp[r * ZB + t] = P;
    // B-fragment image for k5: frag(tile, slice), lane = g*16 + col, elem = ii
    // holds B[k = slice*32 + g*8 + ii][col] = P[r][t].
    const int tile = t >> 4, cl = t & 15;
    const int slice = r >> 5, g = (r >> 3) & 3, ii = r & 7;
    Bimg[((size_t)(tile * 8 + slice) * 64 + (g * 16 + cl)) * 8 + ii] = f_to_bf16u(P);
  }
}

// ---- K3: small tables lt = exp(l_term), ltmz = l_term - logZ
__global__ void k3_tables(const float* __restrict__ logZ, const float* __restrict__ lseZ,
                          const float* __restrict__ lpz, float* __restrict__ lt,
                          float* __restrict__ ltmz) {
  const int l = blockIdx.x; const int z = threadIdx.x;
  const float ll = lpz[z * LB + l] - lseZ[z];
  lt[l * ZB + z] = __expf(ll);
  ltmz[l * ZB + z] = ll - logZ[l * ZB + z];
}

// ---- K4: build shift-aligned emissions, PAIR-PACKED: H2[b][n][z][6] (u32)
__global__ void k4_build(const int* __restrict__ ng, const float* __restrict__ emb,
                         const float* __restrict__ lt, const float* __restrict__ ltmz,
                         unsigned int* __restrict__ H2) {
  const int n = blockIdx.x + 1;
  const int b = blockIdx.y;
  const int z = threadIdx.x;  // 256
  float h[12];
#pragma unroll
  for (int l = 0; l < LB; ++l) {
    const int s = n - 1 - l;
    float hv = 0.f;
    if (s >= 0) {
      const int id = ng[((size_t)l * BB + b) * TB + s];
      if (id == 0) hv = lt[l * ZB + z];
      else if (id != 1) hv = __expf(emb[((size_t)l * VV + id) * ZB + z] + ltmz[l * ZB + z]);
    }
    h[l] = hv;
  }
  h[11] = 0.f;
  unsigned int* dst = H2 + ((size_t)(b * TB + n) * ZB + z) * 6;
#pragma unroll
  for (int i = 0; i < 6; ++i)
    dst[i] = (unsigned int)f_to_bf16u(h[2 * i]) |
             ((unsigned int)f_to_bf16u(h[2 * i + 1]) << 16);
}

#define HLO(u) __uint_as_float((u) << 16)
#define HHI(u) __uint_as_float((u) & 0xFFFF0000u)

// ---- K5: merged single-barrier scan. 256 thr/block (4 waves), one block per b.
// wave w owns tiles {w, w+4, w+8, w+12}; H via 4-slot LDS ring (gload_lds x6,
// size=4, counted vmcnt(12)).
__global__ __launch_bounds__(256, 1)
void k5_forward(const float* __restrict__ Pexp, const unsigned short* __restrict__ Bimg,
                const unsigned int* __restrict__ H2,
                const int* __restrict__ xlen, float* __restrict__ out) {
  const int b = blockIdx.x;
  const int t = threadIdx.x;
  const int w = t >> 6;
  const int lane = t & 63;
  const int col = lane & 15;
  const int g = lane >> 4;
  const int g4 = g << 4;
  const int zb = w * 16 + col;   // tile tt: z = zb + tt*64
  const int zw = zb + g * 64;    // the z this lane publishes

  __shared__ __align__(16) char hring[4 * 6144];         // H step-slab ring
  __shared__ __align__(16) unsigned short S_lds[2][ZB];
  __shared__ __align__(16) float cells[2][4];
  __shared__ float red4[4];

  const char* hbb = (const char*)(H2 + (size_t)b * TB * ZB * 6);

  // stage step-slab np (6144 B) into ring slot np&3: 6 issues x 4 B/lane/wave.
  // Tail (np>511): re-stage slab 511 into its own slot (idempotent, same
  // bytes) so vmcnt counts stay uniform and the counted wait stays sound.
#define STAGE(np)                                                              \
  do {                                                                         \
    const int nps = ((np) <= 511) ? (np) : 511;                                \
    const char* gs = hbb + (size_t)nps * 6144 + w * 1536 + lane * 4;           \
    char* ls = hring + (nps & 3) * 6144 + w * 1536;                            \
    _Pragma("unroll")                                                          \
    for (int k = 0; k < 6; ++k)                                                \
      __builtin_amdgcn_global_load_lds((gm_vt*)(gs + k * 256),                 \
                                       (lds_vt*)(ls + k * 256), 4, 0, 0);      \
  } while (0)

  // resident B = P fragments pinned to AGPRs (4 tiles x 8 slices = 128 AGPR).
  bs8 frag[4][8];
#pragma unroll
  for (int tt = 0; tt < 4; ++tt)
#pragma unroll
    for (int s = 0; s < 8; ++s) {
      frag[tt][s] = *((const bs8*)Bimg + (size_t)((w + 4 * tt) * 8 + s) * 64 + lane);
      asm volatile("" : "+a"(frag[tt][s]));
    }

  const int xl = xlen[b];

  // stage H(2), H(3), H(4) -> slots 2,3,0
  STAGE(2); STAGE(3); STAGE(4);

  // m0 = max_z P[0][z]
  const float p0 = Pexp[zb], p1 = Pexp[zb + 64], p2 = Pexp[zb + 128], p3 = Pexp[zb + 192];
  {
    float pm = rowmax16(fmaxf(fmaxf(p0, p1), fmaxf(p2, p3)));
    if (lane == 0) cells[0][w] = pm;
  }
  __syncthreads();
  const float m0 = fmaxf(fmaxf(cells[0][0], cells[0][1]), fmaxf(cells[0][2], cells[0][3]));
  __syncthreads();
  if (lane == 0) { cells[0][w] = 1.f; cells[1][w] = 1.f; }

  // v-fold state: v[l] = wl[l]*win[l]; d[l] = log wl[l] (guard ring)
  v2f vA[LB], vB[LB];
  float d[LB];
  const float im0 = 1.0f / m0;
  vA[0] = (v2f){p0 * im0, p1 * im0};
  vB[0] = (v2f){p2 * im0, p3 * im0};
#pragma unroll
  for (int l = 1; l < LB; ++l) {
    vA[l] = (v2f){0.f, 0.f}; vB[l] = (v2f){0.f, 0.f}; d[l] = -1e30f;
  }
  d[0] = 0.f;
  float C = __logf(m0), capC = 0.f;
  v2f capA = {0.f, 0.f}, capB = {0.f, 0.f};

  // S(1) = H(1)[l=0] * v[0]  (direct global, one-time)
  {
    const unsigned int u0 = *(const unsigned int*)(hbb + 6144 + (size_t)zb * 24);
    const unsigned int u1 = *(const unsigned int*)(hbb + 6144 + (size_t)(zb + 64) * 24);
    const unsigned int u2 = *(const unsigned int*)(hbb + 6144 + (size_t)(zb + 128) * 24);
    const unsigned int u3 = *(const unsigned int*)(hbb + 6144 + (size_t)(zb + 192) * 24);
    const float S10 = HLO(u0) * vA[0].x;
    const float S11 = HLO(u1) * vA[0].y;
    const float S12 = HLO(u2) * vB[0].x;
    const float S13 = HLO(u3) * vB[0].y;
    if (xl == 1) { capA = (v2f){S10, S11}; capB = (v2f){S12, S13}; capC = C; }
    const float Ssel = (g == 0) ? S10 : (g == 1) ? S11 : (g == 2) ? S12 : S13;
    S_lds[1][zw] = f_to_bf16u(Ssel);
  }
  asm volatile("s_waitcnt vmcnt(0)" ::: "memory");  // prologue drain (once)
  __builtin_amdgcn_sched_barrier(0);
  BAR();

#define REGION(rr, RB, WB, CR, CW)                                             \
  do {                                                                         \
    const float4 cw4 = *(const float4*)cells[CR];                              \
    const bs8* ap = (const bs8*)((const char*)S_lds[RB] + g4);                 \
    bs8 ar[8];                                                                 \
    _Pragma("unroll") for (int s = 0; s < 8; ++s) ar[s] = ap[s * 4];           \
    v4f aP0={0,0,0,0},aP1={0,0,0,0},aP2={0,0,0,0},aP3={0,0,0,0};               \
    v4f aQ0={0,0,0,0},aQ1={0,0,0,0},aQ2={0,0,0,0},aQ3={0,0,0,0};               \
    _Pragma("unroll") for (int s = 0; s < 4; ++s) {                            \
      aP0 = __builtin_amdgcn_mfma_f32_16x16x32_bf16(ar[s], frag[0][s], aP0, 0, 0, 0); \
      aP1 = __builtin_amdgcn_mfma_f32_16x16x32_bf16(ar[s], frag[1][s], aP1, 0, 0, 0); \
      aP2 = __builtin_amdgcn_mfma_f32_16x16x32_bf16(ar[s], frag[2][s], aP2, 0, 0, 0); \
      aP3 = __builtin_amdgcn_mfma_f32_16x16x32_bf16(ar[s], frag[3][s], aP3, 0, 0, 0); \
      aQ0 = __builtin_amdgcn_mfma_f32_16x16x32_bf16(ar[s + 4], frag[0][s + 4], aQ0, 0, 0, 0); \
      aQ1 = __builtin_amdgcn_mfma_f32_16x16x32_bf16(ar[s + 4], frag[1][s + 4], aQ1, 0, 0, 0); \
      aQ2 = __builtin_amdgcn_mfma_f32_16x16x32_bf16(ar[s + 4], frag[2][s + 4], aQ2, 0, 0, 0); \
      aQ3 = __builtin_amdgcn_mfma_f32_16x16x32_bf16(ar[s + 4], frag[3][s + 4], aQ3, 0, 0, 0); \
    }                                                                          \
    /* H(rr+1) from LDS ring (staged >=2 regions ago; landed per vmcnt(12)) */ \
    const char* hz = hring + (((rr) + 1) & 3) * 6144 + zb * 24;                \
    const uint2 h00 = *(const uint2*)(hz + 0);                                 \
    const uint2 h01 = *(const uint2*)(hz + 8);                                 \
    const uint2 h02 = *(const uint2*)(hz + 16);                                \
    const uint2 h10 = *(const uint2*)(hz + 1536);                              \
    const uint2 h11 = *(const uint2*)(hz + 1544);                              \
    const uint2 h12 = *(const uint2*)(hz + 1552);                              \
    const uint2 h20 = *(const uint2*)(hz + 3072);                              \
    const uint2 h21 = *(const uint2*)(hz + 3080);                              \
    const uint2 h22 = *(const uint2*)(hz + 3088);                              \
    const uint2 h30 = *(const uint2*)(hz + 4608);                              \
    const uint2 h31 = *(const uint2*)(hz + 4616);                              \
    const uint2 h32 = *(const uint2*)(hz + 4624);                              \
    const unsigned int w0a = h00.x, w0b = h00.y, w0c = h01.x,                  \
                       w0d = h01.y, w0e = h02.x, w0f = h02.y;                  \
    const unsigned int w1a = h10.x, w1b = h10.y, w1c = h11.x,                  \
                       w1d = h11.y, w1e = h12.x, w1f = h12.y;                  \
    const unsigned int w2a = h20.x, w2b = h20.y, w2c = h21.x,                  \
                       w2d = h21.y, w2e = h22.x, w2f = h22.y;                  \
    const unsigned int w3a = h30.x, w3b = h30.y, w3c = h31.x,                  \
                       w3d = h31.y, w3e = h32.x, w3f = h32.y;                  \
    /* bookkeeping (v-fold, log-free guard) */                                 \
    float mx = fmaxf(fmaxf(fmaxf(cw4.x, cw4.y), fmaxf(cw4.z, cw4.w)), 1e-35f); \
    const float delta = __logf(mx);                                            \
    float dmax = d[0];                                                         \
    _Pragma("unroll") for (int l = 1; l <= 9; ++l) dmax = fmaxf(dmax, d[l]);   \
    const float aa = fmaxf(delta, dmax);                                       \
    const float es = __expf(-aa);                                              \
    const v2f es2 = {es, es};                                                  \
    _Pragma("unroll") for (int l = LB - 1; l >= 1; --l) d[l] = d[l - 1] - aa;  \
    d[0] = delta - aa;                                                         \
    C += aa;                                                                   \
    /* shift v (l>=1) and partial SDOT */                                      \
    v2f SAp = {0.f, 0.f}, SBp = {0.f, 0.f};                                    \
    _Pragma("unroll") for (int l = LB - 1; l >= 1; --l) {                      \
      vA[l] = vA[l - 1] * es2;                                                 \
      vB[l] = vB[l - 1] * es2;                                                 \
      v2f hAl, hBl;                                                            \
      switch (l) {                                                             \
        case 1: hAl = (v2f){HHI(w0a), HHI(w1a)}; hBl = (v2f){HHI(w2a), HHI(w3a)}; break; \
        case 2: hAl = (v2f){HLO(w0b), HLO(w1b)}; hBl = (v2f){HLO(w2b), HLO(w3b)}; break; \
        case 3: hAl = (v2f){HHI(w0b), HHI(w1b)}; hBl = (v2f){HHI(w2b), HHI(w3b)}; break; \
        case 4: hAl = (v2f){HLO(w0c), HLO(w1c)}; hBl = (v2f){HLO(w2c), HLO(w3c)}; break; \
        case 5: hAl = (v2f){HHI(w0c), HHI(w1c)}; hBl = (v2f){HHI(w2c), HHI(w3c)}; break; \
        case 6: hAl = (v2f){HLO(w0d), HLO(w1d)}; hBl = (v2f){HLO(w2d), HLO(w3d)}; break; \
        case 7: hAl = (v2f){HHI(w0d), HHI(w1d)}; hBl = (v2f){HHI(w2d), HHI(w3d)}; break; \
        case 8: hAl = (v2f){HLO(w0e), HLO(w1e)}; hBl = (v2f){HLO(w2e), HLO(w3e)}; break; \
        case 9: hAl = (v2f){HHI(w0e), HHI(w1e)}; hBl = (v2f){HHI(w2e), HHI(w3e)}; break; \
        default: hAl = (v2f){HLO(w0f), HLO(w1f)}; hBl = (v2f){HLO(w2f), HLO(w3f)}; break; \
      }                                                                        \
      SAp = fma2(hAl, vA[l], SAp);                                             \
      SBp = fma2(hBl, vB[l], SBp);                                             \
    }                                                                          \
    /* stage H(rr+4) into slot (rr+4)&3 (consumed region rr+3) */              \
    STAGE((rr) + 4);                                                           \
    /* post-raw short path */                                                  \
    const v2f rawA = {aP0[0] + aQ0[0], aP1[0] + aQ1[0]};                       \
    const v2f rawB = {aP2[0] + aQ2[0], aP3[0] + aQ3[0]};                       \
    vA[0] = rawA * es2;                                                        \
    vB[0] = rawB * es2;                                                        \
    const v2f h0A = {HLO(w0a), HLO(w1a)};                                      \
    const v2f h0B = {HLO(w2a), HLO(w3a)};                                      \
    const v2f SA = fma2(h0A, vA[0], SAp);                                      \
    const v2f SB = fma2(h0B, vB[0], SBp);                                      \
    if ((rr) + 1 == xl) { capA = SA; capB = SB; capC = C; }                    \
    const float Ssel = (g == 0) ? SA.x : (g == 1) ? SA.y : (g == 2) ? SB.x : SB.y; \
    S_lds[WB][zw] = f_to_bf16u(Ssel);                                          \
    {                                                                          \
      const float wm = rowmax16(fmaxf(fmaxf(rawA.x, rawA.y), fmaxf(rawB.x, rawB.y))); \
      if (lane == 0) cells[CW][w] = wm;                                        \
    }                                                                          \
    /* counted wait: stages (rr+4),(rr+3) stay in flight; (rr+2) landed */     \
    asm volatile("s_waitcnt vmcnt(12)" ::: "memory");                          \
    __builtin_amdgcn_sched_barrier(0);                                         \
    BAR();                                                                     \
  } while (0)

#pragma unroll 1
  for (int r = 1; r <= 509; r += 2) {
    REGION(r, 1, 0, 0, 1);
    REGION(r + 1, 0, 1, 1, 0);
  }
#undef REGION
#undef STAGE

  // epilogue: out[b] = capC + log(sum_z cap_z); xl==0 -> 0
  {
    float sv = (capA.x + capA.y) + (capB.x + capB.y);
    sv += __shfl_xor(sv, 1); sv += __shfl_xor(sv, 2);
    sv += __shfl_xor(sv, 4); sv += __shfl_xor(sv, 8);
    if (lane == 0) red4[w] = sv;
  }
  __syncthreads();
  if (t == 0) {
    const float tot = red4[0] + red4[1] + red4[2] + red4[3];
    out[b] = (xl == 0) ? 0.f : (__logf(tot) + capC);
  }
}

extern "C" void kernel_launch(void* const* d_in, const int* in_sizes, int n_in,
                              void* d_out, int out_size, void* d_ws, size_t ws_size,
                              hipStream_t stream) {
  (void)in_sizes; (void)n_in; (void)out_size; (void)ws_size;
  const int* xlen = (const int*)d_in[1];
  const int* ng = (const int*)d_in[2];
  const float* emb = (const float*)d_in[3];
  const float* zpz = (const float*)d_in[4];
  const float* lpz = (const float*)d_in[5];
  float* out = (float*)d_out;

  char* ws = (char*)d_ws;
  unsigned int* H2 = (unsigned int*)ws;
  size_t off = (size_t)BB * TB * ZB * 6 * 4;  // 48 MiB
  float* part = (float*)(ws + off); off += (size_t)LB * NCHUNK * ZB * 4;
  unsigned short* Bimg = (unsigned short*)(ws + off); off += (size_t)16 * 8 * 64 * 8 * 2;
  float* Pexp = (float*)(ws + off); off += (size_t)ZB * ZB * 4;
  float* logZ = (float*)(ws + off); off += (size_t)LB * ZB * 4;
  float* lseZ = (float*)(ws + off); off += (size_t)ZB * 4;
  float* lt = (float*)(ws + off); off += (size_t)LB * ZB * 4;
  float* ltmz = (float*)(ws + off); off += (size_t)LB * ZB * 4;

  k1_sumexp<<<dim3(LB * NCHUNK), dim3(512), 0, stream>>>(emb, part);
  k2_combine<<<dim3(LB + 1 + ZB), dim3(ZB), 0, stream>>>(part, zpz, lpz, logZ, lseZ,
                                                         Pexp, Bimg);
  k3_tables<<<dim3(LB), dim3(ZB), 0, stream>>>(logZ, lseZ, lpz, lt, ltmz);
  k4_build<<<dim3(TB - 1, BB), dim3(ZB), 0, stream>>>(ng, emb, lt, ltmz, H2);
  k5_forward<<<dim3(BB), dim3(256), 0, stream>>>(Pexp, Bimg, H2, xlen, out);
}

// Round 14
// 585.031 us; speedup vs baseline: 1.0389x; 1.0389x over previous
//
#include <hip/hip_runtime.h>

// HSMM forward, scaled linear recurrence.
// R14 = R11 (best variant, absmax 0) + clock/DVFS experiment: k5 launches 256
// blocks; block i redundantly computes chain b = i&15 (identical math), only
// blocks 0-15 write out. Theory: five schedule variants (R7,R9,R10,R11,R13)
// all pinned at ~440us because the chip runs ~1GHz at 1.5% utilization --
// the step is at its structural floor in REAL cycles, and only raising the
// DVFS state can shorten wall time. H2 (48MB) is L3-resident so the 16x
// read amplification is absorbed by L2/L3.
// ws: H2 u32[16][512][256][6] (48MiB); part f32[11][64][256]; Bimg bf16 128KB;
//     Pexp f32[256][256]; logZ[11][256]; lseZ[256]; lt[11][256]; ltmz[11][256].

#define VV 50000
#define ZB 256
#define LB 11
#define BB 16
#define TB 512
#define NCHUNK 64
#define CROWS 782  // ceil(VV/NCHUNK)

typedef float v2f __attribute__((ext_vector_type(2)));
typedef float v4f __attribute__((ext_vector_type(4)));
typedef short bs8 __attribute__((ext_vector_type(8)));

static __device__ __forceinline__ float bf16u_to_f(unsigned short u) {
  return __uint_as_float(((unsigned int)u) << 16);
}
static __device__ __forceinline__ unsigned short f_to_bf16u(float f) {
  unsigned int b = __float_as_uint(f);
  b += 0x7FFFu + ((b >> 16) & 1u);
  return (unsigned short)(b >> 16);
}
static __device__ __forceinline__ v2f fma2(v2f a, v2f b, v2f c) {
  return __builtin_elementwise_fma(a, b, c);
}
template <int CTRL>
static __device__ __forceinline__ float dppmax(float x) {
  const int y = __builtin_amdgcn_update_dpp(0, __float_as_int(x), CTRL, 0xF, 0xF, true);
  return fmaxf(x, __int_as_float(y));
}
static __device__ __forceinline__ float rowmax16(float x) {
  x = dppmax<0xB1>(x);   // quad_perm [1,0,3,2]
  x = dppmax<0x4E>(x);   // quad_perm [2,3,0,1]
  x = dppmax<0x124>(x);  // row_ror:4
  x = dppmax<0x128>(x);  // row_ror:8
  return x;
}

#define BAR() do { asm volatile("s_waitcnt lgkmcnt(0)" ::: "memory"); \
                   __builtin_amdgcn_s_barrier();                      \
                   asm volatile("" ::: "memory"); } while (0)

// ---- K1: per-chunk sum of exp(emb) over v (no-max: emb ~ N(0,1), safe in f32)
__global__ void k1_sumexp(const float* __restrict__ emb, float* __restrict__ part) {
  const int l = blockIdx.x / NCHUNK;
  const int c = blockIdx.x % NCHUNK;
  const int t = threadIdx.x;           // 512 threads
  const int zi = (t & 63) * 4;
  const int ro = t >> 6;               // 0..7
  const int v0 = c * CROWS;
  const int v1 = (v0 + CROWS < VV) ? (v0 + CROWS) : VV;
  const float* base = emb + (size_t)l * VV * ZB;
  float a0 = 0.f, a1 = 0.f, a2 = 0.f, a3 = 0.f;
  int v = v0 + ro;
  for (; v + 24 < v1; v += 32) {
    float4 x0 = *(const float4*)(base + (size_t)(v)*ZB + zi);
    float4 x1 = *(const float4*)(base + (size_t)(v + 8) * ZB + zi);
    float4 x2 = *(const float4*)(base + (size_t)(v + 16) * ZB + zi);
    float4 x3 = *(const float4*)(base + (size_t)(v + 24) * ZB + zi);
    a0 += __expf(x0.x) + __expf(x1.x) + __expf(x2.x) + __expf(x3.x);
    a1 += __expf(x0.y) + __expf(x1.y) + __expf(x2.y) + __expf(x3.y);
    a2 += __expf(x0.z) + __expf(x1.z) + __expf(x2.z) + __expf(x3.z);
    a3 += __expf(x0.w) + __expf(x1.w) + __expf(x2.w) + __expf(x3.w);
  }
  for (; v < v1; v += 8) {
    float4 x0 = *(const float4*)(base + (size_t)v * ZB + zi);
    a0 += __expf(x0.x); a1 += __expf(x0.y); a2 += __expf(x0.z); a3 += __expf(x0.w);
  }
  __shared__ float red[8][ZB];
  red[ro][zi] = a0; red[ro][zi + 1] = a1; red[ro][zi + 2] = a2; red[ro][zi + 3] = a3;
  __syncthreads();
  if (t < ZB) {
    float s = 0.f;
#pragma unroll
    for (int r = 0; r < 8; ++r) s += red[r][t];
    part[((size_t)l * NCHUNK + c) * ZB + t] = s;
  }
}

// ---- K2: combine partials -> logZ; lse over l of l_per_z; Pexp rows + Bimg
__global__ void k2_combine(const float* __restrict__ part, const float* __restrict__ zpz,
                           const float* __restrict__ lpz, float* __restrict__ logZ,
                           float* __restrict__ lseZ, float* __restrict__ Pexp,
                           unsigned short* __restrict__ Bimg) {
  const int bid = blockIdx.x;
  const int t = threadIdx.x;  // 256
  if (bid < LB) {
    float s = 0.f;
    for (int c = 0; c < NCHUNK; ++c) s += part[((size_t)bid * NCHUNK + c) * ZB + t];
    logZ[bid * ZB + t] = __logf(s);
  } else if (bid == LB) {
    float lv[LB]; float m = -1e30f;
#pragma unroll
    for (int l = 0; l < LB; ++l) { lv[l] = lpz[t * LB + l]; m = fmaxf(m, lv[l]); }
    float s = 0.f;
#pragma unroll
    for (int l = 0; l < LB; ++l) s += __expf(lv[l] - m);
    lseZ[t] = m + __logf(s);
  } else {
    const int r = bid - (LB + 1);  // z (row of P)
    const float x = zpz[r * ZB + t];
    __shared__ float sA[4], sB[4];
    float m = x;
#pragma unroll
    for (int off = 32; off >= 1; off >>= 1) m = fmaxf(m, __shfl_xor(m, off, 64));
    if ((t & 63) == 0) sA[t >> 6] = m;
    __syncthreads();
    m = fmaxf(fmaxf(sA[0], sA[1]), fmaxf(sA[2], sA[3]));
    const float e = __expf(x - m);
    float s = e;
#pragma unroll
    for (int off = 32; off >= 1; off >>= 1) s += __shfl_xor(s, off, 64);
    if ((t & 63) == 0) sB[t >> 6] = s;
    __syncthreads();
    const float tot = sB[0] + sB[1] + sB[2] + sB[3];
    const float P = e / tot;
    Pexp[r * ZB + t] = P;
    // B-fragment image for k5: frag(tile, slice), lane = g*16 + col, elem = ii
    // holds B[k = slice*32 + g*8 + ii][col] = P[r][t].
    const int tile = t >> 4, cl = t & 15;
    const int slice = r >> 5, g = (r >> 3) & 3, ii = r & 7;
    Bimg[((size_t)(tile * 8 + slice) * 64 + (g * 16 + cl)) * 8 + ii] = f_to_bf16u(P);
  }
}

// ---- K3: small tables lt = exp(l_term), ltmz = l_term - logZ
__global__ void k3_tables(const float* __restrict__ logZ, const float* __restrict__ lseZ,
                          const float* __restrict__ lpz, float* __restrict__ lt,
                          float* __restrict__ ltmz) {
  const int l = blockIdx.x; const int z = threadIdx.x;
  const float ll = lpz[z * LB + l] - lseZ[z];
  lt[l * ZB + z] = __expf(ll);
  ltmz[l * ZB + z] = ll - logZ[l * ZB + z];
}

// ---- K4: build shift-aligned emissions, PAIR-PACKED: H2[b][n][z][6] (u32)
__global__ void k4_build(const int* __restrict__ ng, const float* __restrict__ emb,
                         const float* __restrict__ lt, const float* __restrict__ ltmz,
                         unsigned int* __restrict__ H2) {
  const int n = blockIdx.x + 1;
  const int b = blockIdx.y;
  const int z = threadIdx.x;  // 256
  float h[12];
#pragma unroll
  for (int l = 0; l < LB; ++l) {
    const int s = n - 1 - l;
    float hv = 0.f;
    if (s >= 0) {
      const int id = ng[((size_t)l * BB + b) * TB + s];
      if (id == 0) hv = lt[l * ZB + z];
      else if (id != 1) hv = __expf(emb[((size_t)l * VV + id) * ZB + z] + ltmz[l * ZB + z]);
    }
    h[l] = hv;
  }
  h[11] = 0.f;
  unsigned int* dst = H2 + ((size_t)(b * TB + n) * ZB + z) * 6;
#pragma unroll
  for (int i = 0; i < 6; ++i)
    dst[i] = (unsigned int)f_to_bf16u(h[2 * i]) |
             ((unsigned int)f_to_bf16u(h[2 * i + 1]) << 16);
}

#define HLO(u) __uint_as_float((u) << 16)
#define HHI(u) __uint_as_float((u) & 0xFFFF0000u)

// ---- K5: merged single-barrier scan. 256 thr/block (4 waves).
// 256 blocks: block i computes chain b = i&15; only blocks 0-15 write out.
__global__ __launch_bounds__(256, 1)
void k5_forward(const float* __restrict__ Pexp, const unsigned short* __restrict__ Bimg,
                const unsigned int* __restrict__ H2,
                const int* __restrict__ xlen, float* __restrict__ out) {
  const int bid = blockIdx.x;
  const int b = bid & 15;
  const int t = threadIdx.x;
  const int w = t >> 6;
  const int lane = t & 63;
  const int col = lane & 15;
  const int g = lane >> 4;
  const int g4 = g << 4;
  const int zb = w * 16 + col;   // tile tt: z = zb + tt*64
  const int zw = zb + g * 64;    // the z this lane publishes

  __shared__ __align__(16) unsigned short S_lds[2][ZB];
  __shared__ __align__(16) float cells[2][4];
  __shared__ float red4[4];

  // resident B = P fragments pinned to AGPRs (4 tiles x 8 slices = 128 AGPR).
  bs8 frag[4][8];
#pragma unroll
  for (int tt = 0; tt < 4; ++tt)
#pragma unroll
    for (int s = 0; s < 8; ++s) {
      frag[tt][s] = *((const bs8*)Bimg + (size_t)((w + 4 * tt) * 8 + s) * 64 + lane);
      asm volatile("" : "+a"(frag[tt][s]));
    }

  const int xl = xlen[b];

  // m0 = max_z P[0][z]
  const float p0 = Pexp[zb], p1 = Pexp[zb + 64], p2 = Pexp[zb + 128], p3 = Pexp[zb + 192];
  {
    float pm = rowmax16(fmaxf(fmaxf(p0, p1), fmaxf(p2, p3)));
    if (lane == 0) cells[0][w] = pm;
  }
  __syncthreads();
  const float m0 = fmaxf(fmaxf(cells[0][0], cells[0][1]), fmaxf(cells[0][2], cells[0][3]));
  __syncthreads();
  if (lane == 0) { cells[0][w] = 1.f; cells[1][w] = 1.f; }

  // v-fold state: v[l] = wl[l]*win[l]; d[l] = log wl[l] (guard ring)
  v2f vA[LB], vB[LB];
  float d[LB];
  const float im0 = 1.0f / m0;
  vA[0] = (v2f){p0 * im0, p1 * im0};
  vB[0] = (v2f){p2 * im0, p3 * im0};
#pragma unroll
  for (int l = 1; l < LB; ++l) {
    vA[l] = (v2f){0.f, 0.f}; vB[l] = (v2f){0.f, 0.f}; d[l] = -1e30f;
  }
  d[0] = 0.f;
  float C = __logf(m0), capC = 0.f;
  v2f capA = {0.f, 0.f}, capB = {0.f, 0.f};

  const unsigned int* hb = H2 + (size_t)b * TB * ZB * 6;

  // S(1) = H(1)[l=0] * v[0]
  {
    const unsigned int u0 = hb[((size_t)1 * ZB + zb) * 6];
    const unsigned int u1 = hb[((size_t)1 * ZB + zb + 64) * 6];
    const unsigned int u2 = hb[((size_t)1 * ZB + zb + 128) * 6];
    const unsigned int u3 = hb[((size_t)1 * ZB + zb + 192) * 6];
    const float S10 = HLO(u0) * vA[0].x;
    const float S11 = HLO(u1) * vA[0].y;
    const float S12 = HLO(u2) * vB[0].x;
    const float S13 = HLO(u3) * vB[0].y;
    if (xl == 1) { capA = (v2f){S10, S11}; capB = (v2f){S12, S13}; capC = C; }
    const float Ssel = (g == 0) ? S10 : (g == 1) ? S11 : (g == 2) ? S12 : S13;
    S_lds[1][zw] = f_to_bf16u(Ssel);
  }

  // H prefetch buffers (distance 2): hE for odd regions, hO for even
  uint2 hE[4][3], hO[4][3];
  const unsigned int* pE = hb + ((size_t)2 * ZB + zb) * 6;
  const unsigned int* pO = hb + ((size_t)3 * ZB + zb) * 6;
#pragma unroll
  for (int tt = 0; tt < 4; ++tt)
#pragma unroll
    for (int i = 0; i < 3; ++i) {
      hE[tt][i] = ((const uint2*)(pE + tt * 384))[i];
      hO[tt][i] = ((const uint2*)(pO + tt * 384))[i];
    }
  pE += 3072;  // advance 2 time steps (2*256*6 u32)
  pO += 3072;
  BAR();

#define REGION(rr, RB, WB, CR, CW, hx, px)                                     \
  do {                                                                         \
    const float4 cw4 = *(const float4*)cells[CR];                              \
    const bs8* ap = (const bs8*)((const char*)S_lds[RB] + g4);                 \
    bs8 ar[8];                                                                 \
    _Pragma("unroll") for (int s = 0; s < 8; ++s) ar[s] = ap[s * 4];           \
    v4f aP0={0,0,0,0},aP1={0,0,0,0},aP2={0,0,0,0},aP3={0,0,0,0};               \
    v4f aQ0={0,0,0,0},aQ1={0,0,0,0},aQ2={0,0,0,0},aQ3={0,0,0,0};               \
    _Pragma("unroll") for (int s = 0; s < 4; ++s) {                            \
      aP0 = __builtin_amdgcn_mfma_f32_16x16x32_bf16(ar[s], frag[0][s], aP0, 0, 0, 0); \
      aP1 = __builtin_amdgcn_mfma_f32_16x16x32_bf16(ar[s], frag[1][s], aP1, 0, 0, 0); \
      aP2 = __builtin_amdgcn_mfma_f32_16x16x32_bf16(ar[s], frag[2][s], aP2, 0, 0, 0); \
      aP3 = __builtin_amdgcn_mfma_f32_16x16x32_bf16(ar[s], frag[3][s], aP3, 0, 0, 0); \
      aQ0 = __builtin_amdgcn_mfma_f32_16x16x32_bf16(ar[s + 4], frag[0][s + 4], aQ0, 0, 0, 0); \
      aQ1 = __builtin_amdgcn_mfma_f32_16x16x32_bf16(ar[s + 4], frag[1][s + 4], aQ1, 0, 0, 0); \
      aQ2 = __builtin_amdgcn_mfma_f32_16x16x32_bf16(ar[s + 4], frag[2][s + 4], aQ2, 0, 0, 0); \
      aQ3 = __builtin_amdgcn_mfma_f32_16x16x32_bf16(ar[s + 4], frag[3][s + 4], aQ3, 0, 0, 0); \
    }                                                                          \
    /* word aliases (read before prefetch overwrites hx) */                    \
    const unsigned int w0a = hx[0][0].x, w0b = hx[0][0].y, w0c = hx[0][1].x,   \
                       w0d = hx[0][1].y, w0e = hx[0][2].x, w0f = hx[0][2].y;   \
    const unsigned int w1a = hx[1][0].x, w1b = hx[1][0].y, w1c = hx[1][1].x,   \
                       w1d = hx[1][1].y, w1e = hx[1][2].x, w1f = hx[1][2].y;   \
    const unsigned int w2a = hx[2][0].x, w2b = hx[2][0].y, w2c = hx[2][1].x,   \
                       w2d = hx[2][1].y, w2e = hx[2][2].x, w2f = hx[2][2].y;   \
    const unsigned int w3a = hx[3][0].x, w3b = hx[3][0].y, w3c = hx[3][1].x,   \
                       w3d = hx[3][1].y, w3e = hx[3][2].x, w3f = hx[3][2].y;   \
    /* bookkeeping (v-fold, log-free guard) */                                 \
    float mx = fmaxf(fmaxf(fmaxf(cw4.x, cw4.y), fmaxf(cw4.z, cw4.w)), 1e-35f); \
    const float delta = __logf(mx);                                            \
    float dmax = d[0];                                                         \
    _Pragma("unroll") for (int l = 1; l <= 9; ++l) dmax = fmaxf(dmax, d[l]);   \
    const float aa = fmaxf(delta, dmax);                                       \
    const float es = __expf(-aa);                                              \
    const v2f es2 = {es, es};                                                  \
    _Pragma("unroll") for (int l = LB - 1; l >= 1; --l) d[l] = d[l - 1] - aa;  \
    d[0] = delta - aa;                                                         \
    C += aa;                                                                   \
    /* shift v (l>=1) and partial SDOT */                                      \
    v2f SAp = {0.f, 0.f}, SBp = {0.f, 0.f};                                    \
    _Pragma("unroll") for (int l = LB - 1; l >= 1; --l) {                      \
      vA[l] = vA[l - 1] * es2;                                                 \
      vB[l] = vB[l - 1] * es2;                                                 \
      v2f hAl, hBl;                                                            \
      switch (l) {                                                             \
        case 1: hAl = (v2f){HHI(w0a), HHI(w1a)}; hBl = (v2f){HHI(w2a), HHI(w3a)}; break; \
        case 2: hAl = (v2f){HLO(w0b), HLO(w1b)}; hBl = (v2f){HLO(w2b), HLO(w3b)}; break; \
        case 3: hAl = (v2f){HHI(w0b), HHI(w1b)}; hBl = (v2f){HHI(w2b), HHI(w3b)}; break; \
        case 4: hAl = (v2f){HLO(w0c), HLO(w1c)}; hBl = (v2f){HLO(w2c), HLO(w3c)}; break; \
        case 5: hAl = (v2f){HHI(w0c), HHI(w1c)}; hBl = (v2f){HHI(w2c), HHI(w3c)}; break; \
        case 6: hAl = (v2f){HLO(w0d), HLO(w1d)}; hBl = (v2f){HLO(w2d), HLO(w3d)}; break; \
        case 7: hAl = (v2f){HHI(w0d), HHI(w1d)}; hBl = (v2f){HHI(w2d), HHI(w3d)}; break; \
        case 8: hAl = (v2f){HLO(w0e), HLO(w1e)}; hBl = (v2f){HLO(w2e), HLO(w3e)}; break; \
        case 9: hAl = (v2f){HHI(w0e), HHI(w1e)}; hBl = (v2f){HHI(w2e), HHI(w3e)}; break; \
        default: hAl = (v2f){HLO(w0f), HLO(w1f)}; hBl = (v2f){HLO(w2f), HLO(w3f)}; break; \
      }                                                                        \
      SAp = fma2(hAl, vA[l], SAp);                                             \
      SBp = fma2(hBl, vB[l], SBp);                                             \
    }                                                                          \
    /* prefetch H for region rr+2 */                                           \
    _Pragma("unroll") for (int tt = 0; tt < 4; ++tt)                           \
      _Pragma("unroll") for (int i = 0; i < 3; ++i)                            \
        hx[tt][i] = ((const uint2*)(px + tt * 384))[i];                        \
    px += 3072;                                                                \
    /* post-raw short path */                                                  \
    const v2f rawA = {aP0[0] + aQ0[0], aP1[0] + aQ1[0]};                       \
    const v2f rawB = {aP2[0] + aQ2[0], aP3[0] + aQ3[0]};                       \
    vA[0] = rawA * es2;                                                        \
    vB[0] = rawB * es2;                                                        \
    const v2f h0A = {HLO(w0a), HLO(w1a)};                                      \
    const v2f h0B = {HLO(w2a), HLO(w3a)};                                      \
    const v2f SA = fma2(h0A, vA[0], SAp);                                      \
    const v2f SB = fma2(h0B, vB[0], SBp);                                      \
    if ((rr) + 1 == xl) { capA = SA; capB = SB; capC = C; }                    \
    const float Ssel = (g == 0) ? SA.x : (g == 1) ? SA.y : (g == 2) ? SB.x : SB.y; \
    S_lds[WB][zw] = f_to_bf16u(Ssel);                                          \
    {                                                                          \
      const float wm = rowmax16(fmaxf(fmaxf(rawA.x, rawA.y), fmaxf(rawB.x, rawB.y))); \
      if (lane == 0) cells[CW][w] = wm;                                        \
    }                                                                          \
    BAR();                                                                     \
  } while (0)

#pragma unroll 1
  for (int r = 1; r <= 509; r += 2) {
    REGION(r, 1, 0, 0, 1, hE, pE);
    REGION(r + 1, 0, 1, 1, 0, hO, pO);
  }
#undef REGION

  // epilogue: out[b] = capC + log(sum_z cap_z); xl==0 -> 0; replicas don't write
  {
    float sv = (capA.x + capA.y) + (capB.x + capB.y);
    sv += __shfl_xor(sv, 1); sv += __shfl_xor(sv, 2);
    sv += __shfl_xor(sv, 4); sv += __shfl_xor(sv, 8);
    if (lane == 0) red4[w] = sv;
  }
  __syncthreads();
  if (t == 0 && bid < 16) {
    const float tot = red4[0] + red4[1] + red4[2] + red4[3];
    out[b] = (xl == 0) ? 0.f : (__logf(tot) + capC);
  }
}

extern "C" void kernel_launch(void* const* d_in, const int* in_sizes, int n_in,
                              void* d_out, int out_size, void* d_ws, size_t ws_size,
                              hipStream_t stream) {
  (void)in_sizes; (void)n_in; (void)out_size; (void)ws_size;
  const int* xlen = (const int*)d_in[1];
  const int* ng = (const int*)d_in[2];
  const float* emb = (const float*)d_in[3];
  const float* zpz = (const float*)d_in[4];
  const float* lpz = (const float*)d_in[5];
  float* out = (float*)d_out;

  char* ws = (char*)d_ws;
  unsigned int* H2 = (unsigned int*)ws;
  size_t off = (size_t)BB * TB * ZB * 6 * 4;  // 48 MiB
  float* part = (float*)(ws + off); off += (size_t)LB * NCHUNK * ZB * 4;
  unsigned short* Bimg = (unsigned short*)(ws + off); off += (size_t)16 * 8 * 64 * 8 * 2;
  float* Pexp = (float*)(ws + off); off += (size_t)ZB * ZB * 4;
  float* logZ = (float*)(ws + off); off += (size_t)LB * ZB * 4;
  float* lseZ = (float*)(ws + off); off += (size_t)ZB * 4;
  float* lt = (float*)(ws + off); off += (size_t)LB * ZB * 4;
  float* ltmz = (float*)(ws + off); off += (size_t)LB * ZB * 4;

  k1_sumexp<<<dim3(LB * NCHUNK), dim3(512), 0, stream>>>(emb, part);
  k2_combine<<<dim3(LB + 1 + ZB), dim3(ZB), 0, stream>>>(part, zpz, lpz, logZ, lseZ,
                                                         Pexp, Bimg);
  k3_tables<<<dim3(LB), dim3(ZB), 0, stream>>>(logZ, lseZ, lpz, lt, ltmz);
  k4_build<<<dim3(TB - 1, BB), dim3(ZB), 0, stream>>>(ng, emb, lt, ltmz, H2);
  k5_forward<<<dim3(256), dim3(256), 0, stream>>>(Pexp, Bimg, H2, xlen, out);
}

// Round 15
// 524.561 us; speedup vs baseline: 1.1587x; 1.1153x over previous
//
#include <hip/hip_runtime.h>

// HSMM forward, scaled linear recurrence.
// R15: uniform-frame window, static slots, lazy rescale. R14's full-occupancy
// counters showed the step is ~40% VALU-issue-bound on bookkeeping. New body:
// (a) all 12 window slots share one scale frame -> wl==1, no d-ring, no
// per-step log/exp; rescale whole window every 4 steps (stale-by-1 max);
// (b) slots are FIXED (slot s holds raw_m, m=s mod 12); k4 stores H rotated
// per n (Hrot[n][s] = H_{(n-1-s)%12}(n), h[11]=0) so S = sum_s hx[s]*win[s]
// with static indices and zero shifts. Period-12 unrolled loop, 42 iters + 5
// tail. MFMA/AGPR-frags/publish/prefetch verbatim from R11 (absmax 0).
// ws: H2 u32[16][512][256][6] (48MiB); part f32[11][64][256]; Bimg bf16 128KB;
//     Pexp f32[256][256]; logZ[11][256]; lseZ[256]; lt[11][256]; ltmz[11][256].

#define VV 50000
#define ZB 256
#define LB 11
#define BB 16
#define TB 512
#define NCHUNK 64
#define CROWS 782  // ceil(VV/NCHUNK)

typedef float v2f __attribute__((ext_vector_type(2)));
typedef float v4f __attribute__((ext_vector_type(4)));
typedef short bs8 __attribute__((ext_vector_type(8)));

static __device__ __forceinline__ float bf16u_to_f(unsigned short u) {
  return __uint_as_float(((unsigned int)u) << 16);
}
static __device__ __forceinline__ unsigned short f_to_bf16u(float f) {
  unsigned int b = __float_as_uint(f);
  b += 0x7FFFu + ((b >> 16) & 1u);
  return (unsigned short)(b >> 16);
}
static __device__ __forceinline__ v2f fma2(v2f a, v2f b, v2f c) {
  return __builtin_elementwise_fma(a, b, c);
}
template <int CTRL>
static __device__ __forceinline__ float dppmax(float x) {
  const int y = __builtin_amdgcn_update_dpp(0, __float_as_int(x), CTRL, 0xF, 0xF, true);
  return fmaxf(x, __int_as_float(y));
}
static __device__ __forceinline__ float rowmax16(float x) {
  x = dppmax<0xB1>(x);   // quad_perm [1,0,3,2]
  x = dppmax<0x4E>(x);   // quad_perm [2,3,0,1]
  x = dppmax<0x124>(x);  // row_ror:4
  x = dppmax<0x128>(x);  // row_ror:8
  return x;
}

#define BAR() do { asm volatile("s_waitcnt lgkmcnt(0)" ::: "memory"); \
                   __builtin_amdgcn_s_barrier();                      \
                   asm volatile("" ::: "memory"); } while (0)

#define HLO(u) __uint_as_float((u) << 16)
#define HHI(u) __uint_as_float((u) & 0xFFFF0000u)

// ---- K1: per-chunk sum of exp(emb) over v (no-max: emb ~ N(0,1), safe in f32)
__global__ void k1_sumexp(const float* __restrict__ emb, float* __restrict__ part) {
  const int l = blockIdx.x / NCHUNK;
  const int c = blockIdx.x % NCHUNK;
  const int t = threadIdx.x;           // 512 threads
  const int zi = (t & 63) * 4;
  const int ro = t >> 6;               // 0..7
  const int v0 = c * CROWS;
  const int v1 = (v0 + CROWS < VV) ? (v0 + CROWS) : VV;
  const float* base = emb + (size_t)l * VV * ZB;
  float a0 = 0.f, a1 = 0.f, a2 = 0.f, a3 = 0.f;
  int v = v0 + ro;
  for (; v + 24 < v1; v += 32) {
    float4 x0 = *(const float4*)(base + (size_t)(v)*ZB + zi);
    float4 x1 = *(const float4*)(base + (size_t)(v + 8) * ZB + zi);
    float4 x2 = *(const float4*)(base + (size_t)(v + 16) * ZB + zi);
    float4 x3 = *(const float4*)(base + (size_t)(v + 24) * ZB + zi);
    a0 += __expf(x0.x) + __expf(x1.x) + __expf(x2.x) + __expf(x3.x);
    a1 += __expf(x0.y) + __expf(x1.y) + __expf(x2.y) + __expf(x3.y);
    a2 += __expf(x0.z) + __expf(x1.z) + __expf(x2.z) + __expf(x3.z);
    a3 += __expf(x0.w) + __expf(x1.w) + __expf(x2.w) + __expf(x3.w);
  }
  for (; v < v1; v += 8) {
    float4 x0 = *(const float4*)(base + (size_t)v * ZB + zi);
    a0 += __expf(x0.x); a1 += __expf(x0.y); a2 += __expf(x0.z); a3 += __expf(x0.w);
  }
  __shared__ float red[8][ZB];
  red[ro][zi] = a0; red[ro][zi + 1] = a1; red[ro][zi + 2] = a2; red[ro][zi + 3] = a3;
  __syncthreads();
  if (t < ZB) {
    float s = 0.f;
#pragma unroll
    for (int r = 0; r < 8; ++r) s += red[r][t];
    part[((size_t)l * NCHUNK + c) * ZB + t] = s;
  }
}

// ---- K2: combine partials -> logZ; lse over l of l_per_z; Pexp rows + Bimg
__global__ void k2_combine(const float* __restrict__ part, const float* __restrict__ zpz,
                           const float* __restrict__ lpz, float* __restrict__ logZ,
                           float* __restrict__ lseZ, float* __restrict__ Pexp,
                           unsigned short* __restrict__ Bimg) {
  const int bid = blockIdx.x;
  const int t = threadIdx.x;  // 256
  if (bid < LB) {
    float s = 0.f;
    for (int c = 0; c < NCHUNK; ++c) s += part[((size_t)bid * NCHUNK + c) * ZB + t];
    logZ[bid * ZB + t] = __logf(s);
  } else if (bid == LB) {
    float lv[LB]; float m = -1e30f;
#pragma unroll
    for (int l = 0; l < LB; ++l) { lv[l] = lpz[t * LB + l]; m = fmaxf(m, lv[l]); }
    float s = 0.f;
#pragma unroll
    for (int l = 0; l < LB; ++l) s += __expf(lv[l] - m);
    lseZ[t] = m + __logf(s);
  } else {
    const int r = bid - (LB + 1);  // z (row of P)
    const float x = zpz[r * ZB + t];
    __shared__ float sA[4], sB[4];
    float m = x;
#pragma unroll
    for (int off = 32; off >= 1; off >>= 1) m = fmaxf(m, __shfl_xor(m, off, 64));
    if ((t & 63) == 0) sA[t >> 6] = m;
    __syncthreads();
    m = fmaxf(fmaxf(sA[0], sA[1]), fmaxf(sA[2], sA[3]));
    const float e = __expf(x - m);
    float s = e;
#pragma unroll
    for (int off = 32; off >= 1; off >>= 1) s += __shfl_xor(s, off, 64);
    if ((t & 63) == 0) sB[t >> 6] = s;
    __syncthreads();
    const float tot = sB[0] + sB[1] + sB[2] + sB[3];
    const float P = e / tot;
    Pexp[r * ZB + t] = P;
    // B-fragment image for k5: frag(tile, slice), lane = g*16 + col, elem = ii
    const int tile = t >> 4, cl = t & 15;
    const int slice = r >> 5, g = (r >> 3) & 3, ii = r & 7;
    Bimg[((size_t)(tile * 8 + slice) * 64 + (g * 16 + cl)) * 8 + ii] = f_to_bf16u(P);
  }
}

// ---- K3: small tables lt = exp(l_term), ltmz = l_term - logZ
__global__ void k3_tables(const float* __restrict__ logZ, const float* __restrict__ lseZ,
                          const float* __restrict__ lpz, float* __restrict__ lt,
                          float* __restrict__ ltmz) {
  const int l = blockIdx.x; const int z = threadIdx.x;
  const float ll = lpz[z * LB + l] - lseZ[z];
  lt[l * ZB + z] = __expf(ll);
  ltmz[l * ZB + z] = ll - logZ[l * ZB + z];
}

// ---- K4: build emissions, ROTATED for fixed slots, pair-packed:
// Hrot[n][z][s] = H_{(n-1-s) mod 12}(n)[z], h[11] == 0.
__global__ void k4_build(const int* __restrict__ ng, const float* __restrict__ emb,
                         const float* __restrict__ lt, const float* __restrict__ ltmz,
                         unsigned int* __restrict__ H2) {
  const int n = blockIdx.x + 1;
  const int b = blockIdx.y;
  const int z = threadIdx.x;  // 256
  float h[12];
#pragma unroll
  for (int l = 0; l < LB; ++l) {
    const int s = n - 1 - l;
    float hv = 0.f;
    if (s >= 0) {
      const int id = ng[((size_t)l * BB + b) * TB + s];
      if (id == 0) hv = lt[l * ZB + z];
      else if (id != 1) hv = __expf(emb[((size_t)l * VV + id) * ZB + z] + ltmz[l * ZB + z]);
    }
    h[l] = hv;
  }
  h[11] = 0.f;
  float hr[12];
#pragma unroll
  for (int s = 0; s < 12; ++s) {
    int idx = (n - 1 - s) % 12; if (idx < 0) idx += 12;
    hr[s] = h[idx];
  }
  unsigned int* dst = H2 + ((size_t)(b * TB + n) * ZB + z) * 6;
#pragma unroll
  for (int i = 0; i < 6; ++i)
    dst[i] = (unsigned int)f_to_bf16u(hr[2 * i]) |
             ((unsigned int)f_to_bf16u(hr[2 * i + 1]) << 16);
}

// ---- K5 body: one scan region (template J = body index in period-12 schedule)
template <int J>
static __device__ __forceinline__ void body_fn(
    int base, int xl, int lane, int w, int g, int g4, int zw, int zb,
    const bs8 (&frag)[4][8], unsigned short (&S_lds)[2][ZB], float (&cells)[4],
    v2f (&vA)[12], v2f (&vB)[12], float& C,
    v2f& capA, v2f& capB, float& capC,
    uint2 (&hx)[4][3], const unsigned int*& px) {
  constexpr int WS = J % 12;               // write slot
  constexpr bool RESC = (J % 4) == 0;      // rescale body
  constexpr bool CELLS = (J % 4) == 3;     // cells-write body
  constexpr int RB = J & 1, WB = (J + 1) & 1;
  const int n = base + J;

  float4 cw4 = {0.f, 0.f, 0.f, 0.f};
  if (RESC) cw4 = *(const float4*)cells;   // early LDS issue

  const bs8* ap = (const bs8*)((const char*)S_lds[RB] + g4);
  bs8 ar[8];
#pragma unroll
  for (int s = 0; s < 8; ++s) ar[s] = ap[s * 4];
  v4f aP0 = {0,0,0,0}, aP1 = {0,0,0,0}, aP2 = {0,0,0,0}, aP3 = {0,0,0,0};
  v4f aQ0 = {0,0,0,0}, aQ1 = {0,0,0,0}, aQ2 = {0,0,0,0}, aQ3 = {0,0,0,0};
#pragma unroll
  for (int s = 0; s < 4; ++s) {
    aP0 = __builtin_amdgcn_mfma_f32_16x16x32_bf16(ar[s], frag[0][s], aP0, 0, 0, 0);
    aP1 = __builtin_amdgcn_mfma_f32_16x16x32_bf16(ar[s], frag[1][s], aP1, 0, 0, 0);
    aP2 = __builtin_amdgcn_mfma_f32_16x16x32_bf16(ar[s], frag[2][s], aP2, 0, 0, 0);
    aP3 = __builtin_amdgcn_mfma_f32_16x16x32_bf16(ar[s], frag[3][s], aP3, 0, 0, 0);
    aQ0 = __builtin_amdgcn_mfma_f32_16x16x32_bf16(ar[s + 4], frag[0][s + 4], aQ0, 0, 0, 0);
    aQ1 = __builtin_amdgcn_mfma_f32_16x16x32_bf16(ar[s + 4], frag[1][s + 4], aQ1, 0, 0, 0);
    aQ2 = __builtin_amdgcn_mfma_f32_16x16x32_bf16(ar[s + 4], frag[2][s + 4], aQ2, 0, 0, 0);
    aQ3 = __builtin_amdgcn_mfma_f32_16x16x32_bf16(ar[s + 4], frag[3][s + 4], aQ3, 0, 0, 0);
  }

  // word aliases (read before prefetch overwrites hx)
  const unsigned int wd0[6] = {hx[0][0].x, hx[0][0].y, hx[0][1].x, hx[0][1].y, hx[0][2].x, hx[0][2].y};
  const unsigned int wd1[6] = {hx[1][0].x, hx[1][0].y, hx[1][1].x, hx[1][1].y, hx[1][2].x, hx[1][2].y};
  const unsigned int wd2[6] = {hx[2][0].x, hx[2][0].y, hx[2][1].x, hx[2][1].y, hx[2][2].x, hx[2][2].y};
  const unsigned int wd3[6] = {hx[3][0].x, hx[3][0].y, hx[3][1].x, hx[3][1].y, hx[3][2].x, hx[3][2].y};

  // partial SDOT over all slots except WS (no shift, no weights)
  v2f SAp = {0.f, 0.f}, SBp = {0.f, 0.f};
#pragma unroll
  for (int s = 0; s < 12; ++s) {
    if (s == WS) continue;
    const int wi = s >> 1;
    v2f hA, hB;
    if (s & 1) {
      hA = (v2f){HHI(wd0[wi]), HHI(wd1[wi])};
      hB = (v2f){HHI(wd2[wi]), HHI(wd3[wi])};
    } else {
      hA = (v2f){HLO(wd0[wi]), HLO(wd1[wi])};
      hB = (v2f){HLO(wd2[wi]), HLO(wd3[wi])};
    }
    SAp = fma2(hA, vA[s], SAp);
    SBp = fma2(hB, vB[s], SBp);
  }

  // prefetch Hrot(n+3) for body n+2
#pragma unroll
  for (int tt = 0; tt < 4; ++tt)
#pragma unroll
    for (int i = 0; i < 3; ++i)
      hx[tt][i] = ((const uint2*)(px + tt * 384))[i];
  px += 3072;

  // post-raw short path
  const v2f rawA = {aP0[0] + aQ0[0], aP1[0] + aQ1[0]};
  const v2f rawB = {aP2[0] + aQ2[0], aP3[0] + aQ3[0]};
  v2f SA, SB;
  {
    constexpr int wi = WS >> 1;
    v2f hA, hB;
    if (WS & 1) {
      hA = (v2f){HHI(wd0[wi]), HHI(wd1[wi])};
      hB = (v2f){HHI(wd2[wi]), HHI(wd3[wi])};
    } else {
      hA = (v2f){HLO(wd0[wi]), HLO(wd1[wi])};
      hB = (v2f){HLO(wd2[wi]), HLO(wd3[wi])};
    }
    SA = fma2(hA, rawA, SAp);
    SB = fma2(hB, rawB, SBp);
  }
  if (RESC) {
    float mx = fmaxf(fmaxf(fmaxf(cw4.x, cw4.y), fmaxf(cw4.z, cw4.w)), 1e-35f);
    const float a = __logf(mx);
    const float es = __expf(-a);
    C += a;
    const v2f es2 = {es, es};
    SA *= es2; SB *= es2;
#pragma unroll
    for (int s = 0; s < 12; ++s) {
      if (s == WS) { vA[s] = rawA * es2; vB[s] = rawB * es2; }
      else { vA[s] *= es2; vB[s] *= es2; }
    }
  } else {
    vA[WS] = rawA; vB[WS] = rawB;
  }
  if (n + 1 == xl) { capA = SA; capB = SB; capC = C; }
  const float Ssel = (g == 0) ? SA.x : (g == 1) ? SA.y : (g == 2) ? SB.x : SB.y;
  S_lds[WB][zw] = f_to_bf16u(Ssel);
  if (CELLS) {
    const float wm = rowmax16(fmaxf(fmaxf(rawA.x, rawA.y), fmaxf(rawB.x, rawB.y)));
    if (lane == 0) cells[w] = wm;
  }
  BAR();
}

// ---- K5: merged single-barrier scan. 256 thr/block (4 waves), 16 blocks.
__global__ __launch_bounds__(256, 1)
void k5_forward(const float* __restrict__ Pexp, const unsigned short* __restrict__ Bimg,
                const unsigned int* __restrict__ H2,
                const int* __restrict__ xlen, float* __restrict__ out) {
  const int b = blockIdx.x;
  const int t = threadIdx.x;
  const int w = t >> 6;
  const int lane = t & 63;
  const int col = lane & 15;
  const int g = lane >> 4;
  const int g4 = g << 4;
  const int zb = w * 16 + col;
  const int zw = zb + g * 64;

  __shared__ __align__(16) unsigned short S_lds[2][ZB];
  __shared__ __align__(16) float cells[4];
  __shared__ float redm[4];
  __shared__ float red4[4];

  // resident B = P fragments pinned to AGPRs (4 tiles x 8 slices = 128 AGPR).
  bs8 frag[4][8];
#pragma unroll
  for (int tt = 0; tt < 4; ++tt)
#pragma unroll
    for (int s = 0; s < 8; ++s) {
      frag[tt][s] = *((const bs8*)Bimg + (size_t)((w + 4 * tt) * 8 + s) * 64 + lane);
      asm volatile("" : "+a"(frag[tt][s]));
    }

  const int xl = xlen[b];

  // m0 = max_z P[0][z]
  const float p0 = Pexp[zb], p1 = Pexp[zb + 64], p2 = Pexp[zb + 128], p3 = Pexp[zb + 192];
  {
    float pm = rowmax16(fmaxf(fmaxf(p0, p1), fmaxf(p2, p3)));
    if (lane == 0) redm[w] = pm;
  }
  __syncthreads();
  const float m0 = fmaxf(fmaxf(redm[0], redm[1]), fmaxf(redm[2], redm[3]));
  __syncthreads();

  // window slots (common frame)
  v2f vA[12], vB[12];
  const float im0 = 1.0f / m0;
  vA[0] = (v2f){p0 * im0, p1 * im0};
  vB[0] = (v2f){p2 * im0, p3 * im0};
#pragma unroll
  for (int s = 1; s < 12; ++s) { vA[s] = (v2f){0.f, 0.f}; vB[s] = (v2f){0.f, 0.f}; }
  float C = __logf(m0), capC = 0.f;
  v2f capA = {0.f, 0.f}, capB = {0.f, 0.f};

  const unsigned int* hb = H2 + (size_t)b * TB * ZB * 6;

  // S(1) = Hrot(1)[slot 0] * win_0   (slot 0 is lo of word 0)
  {
    const unsigned int u0 = hb[((size_t)1 * ZB + zb) * 6];
    const unsigned int u1 = hb[((size_t)1 * ZB + zb + 64) * 6];
    const unsigned int u2 = hb[((size_t)1 * ZB + zb + 128) * 6];
    const unsigned int u3 = hb[((size_t)1 * ZB + zb + 192) * 6];
    const float S10 = HLO(u0) * vA[0].x;
    const float S11 = HLO(u1) * vA[0].y;
    const float S12 = HLO(u2) * vB[0].x;
    const float S13 = HLO(u3) * vB[0].y;
    if (xl == 1) { capA = (v2f){S10, S11}; capB = (v2f){S12, S13}; capC = C; }
    const float Ssel = (g == 0) ? S10 : (g == 1) ? S11 : (g == 2) ? S12 : S13;
    S_lds[1][zw] = f_to_bf16u(Ssel);
  }

  // H prefetch buffers (distance 2): hE for odd bodies, hO for even
  uint2 hE[4][3], hO[4][3];
  const unsigned int* pE = hb + ((size_t)2 * ZB + zb) * 6;
  const unsigned int* pO = hb + ((size_t)3 * ZB + zb) * 6;
#pragma unroll
  for (int tt = 0; tt < 4; ++tt)
#pragma unroll
    for (int i = 0; i < 3; ++i) {
      hE[tt][i] = ((const uint2*)(pE + tt * 384))[i];
      hO[tt][i] = ((const uint2*)(pO + tt * 384))[i];
    }
  pE += 3072;
  pO += 3072;
  BAR();

#define BODYARGS xl, lane, w, g, g4, zw, zb, frag, S_lds, cells, vA, vB, C, capA, capB, capC
#pragma unroll 1
  for (int k = 0; k < 42; ++k) {
    const int base = 12 * k;
    body_fn<1>(base, BODYARGS, hE, pE);
    body_fn<2>(base, BODYARGS, hO, pO);
    body_fn<3>(base, BODYARGS, hE, pE);
    body_fn<4>(base, BODYARGS, hO, pO);
    body_fn<5>(base, BODYARGS, hE, pE);
    body_fn<6>(base, BODYARGS, hO, pO);
    body_fn<7>(base, BODYARGS, hE, pE);
    body_fn<8>(base, BODYARGS, hO, pO);
    body_fn<9>(base, BODYARGS, hE, pE);
    body_fn<10>(base, BODYARGS, hO, pO);
    body_fn<11>(base, BODYARGS, hE, pE);
    body_fn<12>(base, BODYARGS, hO, pO);
  }
  // tail: n = 505..509 (xl <= 510 -> last needed capture is at body n = 509)
  body_fn<1>(504, BODYARGS, hE, pE);
  body_fn<2>(504, BODYARGS, hO, pO);
  body_fn<3>(504, BODYARGS, hE, pE);
  body_fn<4>(504, BODYARGS, hO, pO);
  body_fn<5>(504, BODYARGS, hE, pE);
#undef BODYARGS

  // epilogue: out[b] = capC + log(sum_z cap_z); xl==0 -> 0
  {
    float sv = (capA.x + capA.y) + (capB.x + capB.y);
    sv += __shfl_xor(sv, 1); sv += __shfl_xor(sv, 2);
    sv += __shfl_xor(sv, 4); sv += __shfl_xor(sv, 8);
    if (lane == 0) red4[w] = sv;
  }
  __syncthreads();
  if (t == 0) {
    const float tot = red4[0] + red4[1] + red4[2] + red4[3];
    out[b] = (xl == 0) ? 0.f : (__logf(tot) + capC);
  }
}

extern "C" void kernel_launch(void* const* d_in, const int* in_sizes, int n_in,
                              void* d_out, int out_size, void* d_ws, size_t ws_size,
                              hipStream_t stream) {
  (void)in_sizes; (void)n_in; (void)out_size; (void)ws_size;
  const int* xlen = (const int*)d_in[1];
  const int* ng = (const int*)d_in[2];
  const float* emb = (const float*)d_in[3];
  const float* zpz = (const float*)d_in[4];
  const float* lpz = (const float*)d_in[5];
  float* out = (float*)d_out;

  char* ws = (char*)d_ws;
  unsigned int* H2 = (unsigned int*)ws;
  size_t off = (size_t)BB * TB * ZB * 6 * 4;  // 48 MiB
  float* part = (float*)(ws + off); off += (size_t)LB * NCHUNK * ZB * 4;
  unsigned short* Bimg = (unsigned short*)(ws + off); off += (size_t)16 * 8 * 64 * 8 * 2;
  float* Pexp = (float*)(ws + off); off += (size_t)ZB * ZB * 4;
  float* logZ = (float*)(ws + off); off += (size_t)LB * ZB * 4;
  float* lseZ = (float*)(ws + off); off += (size_t)ZB * 4;
  float* lt = (float*)(ws + off); off += (size_t)LB * ZB * 4;
  float* ltmz = (float*)(ws + off); off += (size_t)LB * ZB * 4;

  k1_sumexp<<<dim3(LB * NCHUNK), dim3(512), 0, stream>>>(emb, part);
  k2_combine<<<dim3(LB + 1 + ZB), dim3(ZB), 0, stream>>>(part, zpz, lpz, logZ, lseZ,
                                                         Pexp, Bimg);
  k3_tables<<<dim3(LB), dim3(ZB), 0, stream>>>(logZ, lseZ, lpz, lt, ltmz);
  k4_build<<<dim3(TB - 1, BB), dim3(ZB), 0, stream>>>(ng, emb, lt, ltmz, H2);
  k5_forward<<<dim3(BB), dim3(256), 0, stream>>>(Pexp, Bimg, H2, xlen, out);
}

// Round 16
// 417.562 us; speedup vs baseline: 1.4556x; 1.2562x over previous
//
#include <hip/hip_runtime.h>

// HSMM forward, scaled linear recurrence.
// R16: de-duplicate the 4x redundant g-group work. MFMA D-layout replicates
// raw across the 4 row-groups, so R15 had every lane tracking 4 z's with its
// 3 sibling lanes doing IDENTICAL work. Now lane owns ONE z (zw, the one it
// publishes): window 12 scalars, SDOT 11 fma + 6 unpacks, H prefetch 3 uint2
// (4x less load traffic), rescale 12 ops. raw for the write-slot selected
// from the 4 tile accs by g (3 cndmask). + per-block early exit at
// ceil((xl-1)/12) dozens. MFMA/AGPR frags/single-barrier from R15 (absmax 0).
// ws: H2 u32[16][512][256][6] (48MiB); part f32[11][64][256]; Bimg bf16 128KB;
//     Pexp f32[256][256]; logZ[11][256]; lseZ[256]; lt[11][256]; ltmz[11][256].

#define VV 50000
#define ZB 256
#define LB 11
#define BB 16
#define TB 512
#define NCHUNK 64
#define CROWS 782  // ceil(VV/NCHUNK)

typedef float v2f __attribute__((ext_vector_type(2)));
typedef float v4f __attribute__((ext_vector_type(4)));
typedef short bs8 __attribute__((ext_vector_type(8)));

static __device__ __forceinline__ float bf16u_to_f(unsigned short u) {
  return __uint_as_float(((unsigned int)u) << 16);
}
static __device__ __forceinline__ unsigned short f_to_bf16u(float f) {
  unsigned int b = __float_as_uint(f);
  b += 0x7FFFu + ((b >> 16) & 1u);
  return (unsigned short)(b >> 16);
}
template <int CTRL>
static __device__ __forceinline__ float dppmax(float x) {
  const int y = __builtin_amdgcn_update_dpp(0, __float_as_int(x), CTRL, 0xF, 0xF, true);
  return fmaxf(x, __int_as_float(y));
}
static __device__ __forceinline__ float rowmax16(float x) {
  x = dppmax<0xB1>(x);   // quad_perm [1,0,3,2]
  x = dppmax<0x4E>(x);   // quad_perm [2,3,0,1]
  x = dppmax<0x124>(x);  // row_ror:4
  x = dppmax<0x128>(x);  // row_ror:8
  return x;
}

#define BAR() do { asm volatile("s_waitcnt lgkmcnt(0)" ::: "memory"); \
                   __builtin_amdgcn_s_barrier();                      \
                   asm volatile("" ::: "memory"); } while (0)

#define HLO(u) __uint_as_float((u) << 16)
#define HHI(u) __uint_as_float((u) & 0xFFFF0000u)

// ---- K1: per-chunk sum of exp(emb) over v (no-max: emb ~ N(0,1), safe in f32)
__global__ void k1_sumexp(const float* __restrict__ emb, float* __restrict__ part) {
  const int l = blockIdx.x / NCHUNK;
  const int c = blockIdx.x % NCHUNK;
  const int t = threadIdx.x;           // 512 threads
  const int zi = (t & 63) * 4;
  const int ro = t >> 6;               // 0..7
  const int v0 = c * CROWS;
  const int v1 = (v0 + CROWS < VV) ? (v0 + CROWS) : VV;
  const float* base = emb + (size_t)l * VV * ZB;
  float a0 = 0.f, a1 = 0.f, a2 = 0.f, a3 = 0.f;
  int v = v0 + ro;
  for (; v + 24 < v1; v += 32) {
    float4 x0 = *(const float4*)(base + (size_t)(v)*ZB + zi);
    float4 x1 = *(const float4*)(base + (size_t)(v + 8) * ZB + zi);
    float4 x2 = *(const float4*)(base + (size_t)(v + 16) * ZB + zi);
    float4 x3 = *(const float4*)(base + (size_t)(v + 24) * ZB + zi);
    a0 += __expf(x0.x) + __expf(x1.x) + __expf(x2.x) + __expf(x3.x);
    a1 += __expf(x0.y) + __expf(x1.y) + __expf(x2.y) + __expf(x3.y);
    a2 += __expf(x0.z) + __expf(x1.z) + __expf(x2.z) + __expf(x3.z);
    a3 += __expf(x0.w) + __expf(x1.w) + __expf(x2.w) + __expf(x3.w);
  }
  for (; v < v1; v += 8) {
    float4 x0 = *(const float4*)(base + (size_t)v * ZB + zi);
    a0 += __expf(x0.x); a1 += __expf(x0.y); a2 += __expf(x0.z); a3 += __expf(x0.w);
  }
  __shared__ float red[8][ZB];
  red[ro][zi] = a0; red[ro][zi + 1] = a1; red[ro][zi + 2] = a2; red[ro][zi + 3] = a3;
  __syncthreads();
  if (t < ZB) {
    float s = 0.f;
#pragma unroll
    for (int r = 0; r < 8; ++r) s += red[r][t];
    part[((size_t)l * NCHUNK + c) * ZB + t] = s;
  }
}

// ---- K2: combine partials -> logZ; lse over l of l_per_z; Pexp rows + Bimg
__global__ void k2_combine(const float* __restrict__ part, const float* __restrict__ zpz,
                           const float* __restrict__ lpz, float* __restrict__ logZ,
                           float* __restrict__ lseZ, float* __restrict__ Pexp,
                           unsigned short* __restrict__ Bimg) {
  const int bid = blockIdx.x;
  const int t = threadIdx.x;  // 256
  if (bid < LB) {
    float s = 0.f;
    for (int c = 0; c < NCHUNK; ++c) s += part[((size_t)bid * NCHUNK + c) * ZB + t];
    logZ[bid * ZB + t] = __logf(s);
  } else if (bid == LB) {
    float lv[LB]; float m = -1e30f;
#pragma unroll
    for (int l = 0; l < LB; ++l) { lv[l] = lpz[t * LB + l]; m = fmaxf(m, lv[l]); }
    float s = 0.f;
#pragma unroll
    for (int l = 0; l < LB; ++l) s += __expf(lv[l] - m);
    lseZ[t] = m + __logf(s);
  } else {
    const int r = bid - (LB + 1);  // z (row of P)
    const float x = zpz[r * ZB + t];
    __shared__ float sA[4], sB[4];
    float m = x;
#pragma unroll
    for (int off = 32; off >= 1; off >>= 1) m = fmaxf(m, __shfl_xor(m, off, 64));
    if ((t & 63) == 0) sA[t >> 6] = m;
    __syncthreads();
    m = fmaxf(fmaxf(sA[0], sA[1]), fmaxf(sA[2], sA[3]));
    const float e = __expf(x - m);
    float s = e;
#pragma unroll
    for (int off = 32; off >= 1; off >>= 1) s += __shfl_xor(s, off, 64);
    if ((t & 63) == 0) sB[t >> 6] = s;
    __syncthreads();
    const float tot = sB[0] + sB[1] + sB[2] + sB[3];
    const float P = e / tot;
    Pexp[r * ZB + t] = P;
    // B-fragment image for k5: frag(tile, slice), lane = g*16 + col, elem = ii
    const int tile = t >> 4, cl = t & 15;
    const int slice = r >> 5, g = (r >> 3) & 3, ii = r & 7;
    Bimg[((size_t)(tile * 8 + slice) * 64 + (g * 16 + cl)) * 8 + ii] = f_to_bf16u(P);
  }
}

// ---- K3: small tables lt = exp(l_term), ltmz = l_term - logZ
__global__ void k3_tables(const float* __restrict__ logZ, const float* __restrict__ lseZ,
                          const float* __restrict__ lpz, float* __restrict__ lt,
                          float* __restrict__ ltmz) {
  const int l = blockIdx.x; const int z = threadIdx.x;
  const float ll = lpz[z * LB + l] - lseZ[z];
  lt[l * ZB + z] = __expf(ll);
  ltmz[l * ZB + z] = ll - logZ[l * ZB + z];
}

// ---- K4: build emissions, ROTATED for fixed slots, pair-packed:
// Hrot[n][z][s] = H_{(n-1-s) mod 12}(n)[z], h[11] == 0.
__global__ void k4_build(const int* __restrict__ ng, const float* __restrict__ emb,
                         const float* __restrict__ lt, const float* __restrict__ ltmz,
                         unsigned int* __restrict__ H2) {
  const int n = blockIdx.x + 1;
  const int b = blockIdx.y;
  const int z = threadIdx.x;  // 256
  float h[12];
#pragma unroll
  for (int l = 0; l < LB; ++l) {
    const int s = n - 1 - l;
    float hv = 0.f;
    if (s >= 0) {
      const int id = ng[((size_t)l * BB + b) * TB + s];
      if (id == 0) hv = lt[l * ZB + z];
      else if (id != 1) hv = __expf(emb[((size_t)l * VV + id) * ZB + z] + ltmz[l * ZB + z]);
    }
    h[l] = hv;
  }
  h[11] = 0.f;
  float hr[12];
#pragma unroll
  for (int s = 0; s < 12; ++s) {
    int idx = (n - 1 - s) % 12; if (idx < 0) idx += 12;
    hr[s] = h[idx];
  }
  unsigned int* dst = H2 + ((size_t)(b * TB + n) * ZB + z) * 6;
#pragma unroll
  for (int i = 0; i < 6; ++i)
    dst[i] = (unsigned int)f_to_bf16u(hr[2 * i]) |
             ((unsigned int)f_to_bf16u(hr[2 * i + 1]) << 16);
}

// ---- K5 body: one scan region; lane owns ONE z (zw).
template <int J>
static __device__ __forceinline__ void body_fn(
    int base, int xl, int lane, int w, int g, int g4, int zw,
    const bs8 (&frag)[4][8], unsigned short (&S_lds)[2][ZB], float (&cells)[4],
    float (&vwin)[12], float& C, float& capS, float& capC,
    uint2 (&hx)[3], const unsigned int*& px) {
  constexpr int WS = J % 12;               // write slot
  constexpr bool RESC = (J % 4) == 0;      // rescale body
  constexpr bool CELLS = (J % 4) == 3;     // cells-write body
  constexpr int RB = J & 1, WB = (J + 1) & 1;
  const int n = base + J;

  float4 cw4 = {0.f, 0.f, 0.f, 0.f};
  if (RESC) cw4 = *(const float4*)cells;   // early LDS issue

  const bs8* ap = (const bs8*)((const char*)S_lds[RB] + g4);
  bs8 ar[8];
#pragma unroll
  for (int s = 0; s < 8; ++s) ar[s] = ap[s * 4];
  v4f aP0 = {0,0,0,0}, aP1 = {0,0,0,0}, aP2 = {0,0,0,0}, aP3 = {0,0,0,0};
  v4f aQ0 = {0,0,0,0}, aQ1 = {0,0,0,0}, aQ2 = {0,0,0,0}, aQ3 = {0,0,0,0};
#pragma unroll
  for (int s = 0; s < 4; ++s) {
    aP0 = __builtin_amdgcn_mfma_f32_16x16x32_bf16(ar[s], frag[0][s], aP0, 0, 0, 0);
    aP1 = __builtin_amdgcn_mfma_f32_16x16x32_bf16(ar[s], frag[1][s], aP1, 0, 0, 0);
    aP2 = __builtin_amdgcn_mfma_f32_16x16x32_bf16(ar[s], frag[2][s], aP2, 0, 0, 0);
    aP3 = __builtin_amdgcn_mfma_f32_16x16x32_bf16(ar[s], frag[3][s], aP3, 0, 0, 0);
    aQ0 = __builtin_amdgcn_mfma_f32_16x16x32_bf16(ar[s + 4], frag[0][s + 4], aQ0, 0, 0, 0);
    aQ1 = __builtin_amdgcn_mfma_f32_16x16x32_bf16(ar[s + 4], frag[1][s + 4], aQ1, 0, 0, 0);
    aQ2 = __builtin_amdgcn_mfma_f32_16x16x32_bf16(ar[s + 4], frag[2][s + 4], aQ2, 0, 0, 0);
    aQ3 = __builtin_amdgcn_mfma_f32_16x16x32_bf16(ar[s + 4], frag[3][s + 4], aQ3, 0, 0, 0);
  }

  // this lane's 6 H-words (read before prefetch overwrites hx)
  const unsigned int wd0 = hx[0].x, wd1 = hx[0].y, wd2 = hx[1].x,
                     wd3 = hx[1].y, wd4 = hx[2].x, wd5 = hx[2].y;

  // partial SDOT over all slots except WS (single z, scalar fma)
  float Sp = 0.f;
#pragma unroll
  for (int s = 0; s < 12; ++s) {
    if (s == WS) continue;
    const int wi = s >> 1;
    const unsigned int wdv = wi == 0 ? wd0 : wi == 1 ? wd1 : wi == 2 ? wd2
                           : wi == 3 ? wd3 : wi == 4 ? wd4 : wd5;
    const float h = (s & 1) ? HHI(wdv) : HLO(wdv);
    Sp = fmaf(h, vwin[s], Sp);
  }
  constexpr int WWI = WS >> 1;
  const unsigned int wdW = WWI == 0 ? wd0 : WWI == 1 ? wd1 : WWI == 2 ? wd2
                         : WWI == 3 ? wd3 : WWI == 4 ? wd4 : wd5;
  const float hWS = (WS & 1) ? HHI(wdW) : HLO(wdW);

  // prefetch Hrot(n+3) for body n+2 (this lane's z only: 3 uint2)
  hx[0] = ((const uint2*)px)[0];
  hx[1] = ((const uint2*)px)[1];
  hx[2] = ((const uint2*)px)[2];
  px += 3072;

  // raws for the wave's 4 tiles (replicated across g-groups)
  const float r0 = aP0[0] + aQ0[0];
  const float r1 = aP1[0] + aQ1[0];
  const float r2 = aP2[0] + aQ2[0];
  const float r3 = aP3[0] + aQ3[0];
  const float rsel = (g == 0) ? r0 : (g == 1) ? r1 : (g == 2) ? r2 : r3;

  float S;
  if (RESC) {
    float mx = fmaxf(fmaxf(fmaxf(cw4.x, cw4.y), fmaxf(cw4.z, cw4.w)), 1e-35f);
    const float a = __logf(mx);
    const float es = __expf(-a);
    C += a;
    S = fmaf(hWS, rsel, Sp) * es;
#pragma unroll
    for (int s = 0; s < 12; ++s)
      vwin[s] = ((s == WS) ? rsel : vwin[s]) * es;
  } else {
    S = fmaf(hWS, rsel, Sp);
    vwin[WS] = rsel;
  }
  if (n + 1 == xl) { capS = S; capC = C; }
  S_lds[WB][zw] = f_to_bf16u(S);
  if (CELLS) {
    const float wm = rowmax16(fmaxf(fmaxf(r0, r1), fmaxf(r2, r3)));
    if (lane == 0) cells[w] = wm;
  }
  BAR();
}

// ---- K5: merged single-barrier scan. 256 thr/block (4 waves), 16 blocks.
__global__ __launch_bounds__(256, 1)
void k5_forward(const float* __restrict__ Pexp, const unsigned short* __restrict__ Bimg,
                const unsigned int* __restrict__ H2,
                const int* __restrict__ xlen, float* __restrict__ out) {
  const int b = blockIdx.x;
  const int t = threadIdx.x;
  const int w = t >> 6;
  const int lane = t & 63;
  const int col = lane & 15;
  const int g = lane >> 4;
  const int g4 = g << 4;
  const int zw = w * 16 + col + g * 64;   // the ONE z this lane owns

  __shared__ __align__(16) unsigned short S_lds[2][ZB];
  __shared__ __align__(16) float cells[4];
  __shared__ float redm[4];
  __shared__ float red4[4];

  // resident B = P fragments pinned to AGPRs (4 tiles x 8 slices = 128 AGPR).
  bs8 frag[4][8];
#pragma unroll
  for (int tt = 0; tt < 4; ++tt)
#pragma unroll
    for (int s = 0; s < 8; ++s) {
      frag[tt][s] = *((const bs8*)Bimg + (size_t)((w + 4 * tt) * 8 + s) * 64 + lane);
      asm volatile("" : "+a"(frag[tt][s]));
    }

  const int xl = xlen[b];

  // m0 = max_z P[0][z]  (full 64-lane reduce, then cross-wave)
  const float p = Pexp[zw];
  {
    float pm = p;
#pragma unroll
    for (int off = 32; off >= 1; off >>= 1) pm = fmaxf(pm, __shfl_xor(pm, off, 64));
    if (lane == 0) redm[w] = pm;
  }
  __syncthreads();
  const float m0 = fmaxf(fmaxf(redm[0], redm[1]), fmaxf(redm[2], redm[3]));
  __syncthreads();

  // window slots (common frame), one z per lane
  float vwin[12];
  vwin[0] = p / m0;
#pragma unroll
  for (int s = 1; s < 12; ++s) vwin[s] = 0.f;
  float C = __logf(m0), capC = 0.f, capS = 0.f;

  const unsigned int* hb = H2 + (size_t)b * TB * ZB * 6;

  // S(1) = Hrot(1)[slot 0] * win_0
  {
    const unsigned int u = hb[((size_t)1 * ZB + zw) * 6];
    const float S1 = HLO(u) * vwin[0];
    if (xl == 1) { capS = S1; capC = C; }
    S_lds[1][zw] = f_to_bf16u(S1);
  }

  // H prefetch buffers (distance 2): hE for odd bodies, hO for even
  uint2 hE[3], hO[3];
  const unsigned int* pE = hb + ((size_t)2 * ZB + zw) * 6;
  const unsigned int* pO = hb + ((size_t)3 * ZB + zw) * 6;
#pragma unroll
  for (int i = 0; i < 3; ++i) {
    hE[i] = ((const uint2*)pE)[i];
    hO[i] = ((const uint2*)pO)[i];
  }
  pE += 3072;  // advance 2 time steps (2*256*6 u32)
  pO += 3072;
  BAR();

  // bodies needed: n = 1 .. xl-1 (capture at n+1 == xl); xl<=1 handled above.
  const int nb = (xl >= 2) ? (xl - 1) : 0;
  const int kmax = (nb + 11) / 12;

#define BODYARGS xl, lane, w, g, g4, zw, frag, S_lds, cells, vwin, C, capS, capC
#pragma unroll 1
  for (int k = 0; k < kmax; ++k) {
    const int base = 12 * k;
    body_fn<1>(base, BODYARGS, hE, pE);
    body_fn<2>(base, BODYARGS, hO, pO);
    body_fn<3>(base, BODYARGS, hE, pE);
    body_fn<4>(base, BODYARGS, hO, pO);
    body_fn<5>(base, BODYARGS, hE, pE);
    body_fn<6>(base, BODYARGS, hO, pO);
    body_fn<7>(base, BODYARGS, hE, pE);
    body_fn<8>(base, BODYARGS, hO, pO);
    body_fn<9>(base, BODYARGS, hE, pE);
    body_fn<10>(base, BODYARGS, hO, pO);
    body_fn<11>(base, BODYARGS, hE, pE);
    body_fn<12>(base, BODYARGS, hO, pO);
  }
#undef BODYARGS

  // epilogue: out[b] = capC + log(sum_z capS_z); xl==0 -> 0
  {
    float sv = capS;
#pragma unroll
    for (int off = 32; off >= 1; off >>= 1) sv += __shfl_xor(sv, off, 64);
    if (lane == 0) red4[w] = sv;
  }
  __syncthreads();
  if (t == 0) {
    const float tot = red4[0] + red4[1] + red4[2] + red4[3];
    out[b] = (xl == 0) ? 0.f : (__logf(tot) + capC);
  }
}

extern "C" void kernel_launch(void* const* d_in, const int* in_sizes, int n_in,
                              void* d_out, int out_size, void* d_ws, size_t ws_size,
                              hipStream_t stream) {
  (void)in_sizes; (void)n_in; (void)out_size; (void)ws_size;
  const int* xlen = (const int*)d_in[1];
  const int* ng = (const int*)d_in[2];
  const float* emb = (const float*)d_in[3];
  const float* zpz = (const float*)d_in[4];
  const float* lpz = (const float*)d_in[5];
  float* out = (float*)d_out;

  char* ws = (char*)d_ws;
  unsigned int* H2 = (unsigned int*)ws;
  size_t off = (size_t)BB * TB * ZB * 6 * 4;  // 48 MiB
  float* part = (float*)(ws + off); off += (size_t)LB * NCHUNK * ZB * 4;
  unsigned short* Bimg = (unsigned short*)(ws + off); off += (size_t)16 * 8 * 64 * 8 * 2;
  float* Pexp = (float*)(ws + off); off += (size_t)ZB * ZB * 4;
  float* logZ = (float*)(ws + off); off += (size_t)LB * ZB * 4;
  float* lseZ = (float*)(ws + off); off += (size_t)ZB * 4;
  float* lt = (float*)(ws + off); off += (size_t)LB * ZB * 4;
  float* ltmz = (float*)(ws + off); off += (size_t)LB * ZB * 4;

  k1_sumexp<<<dim3(LB * NCHUNK), dim3(512), 0, stream>>>(emb, part);
  k2_combine<<<dim3(LB + 1 + ZB), dim3(ZB), 0, stream>>>(part, zpz, lpz, logZ, lseZ,
                                                         Pexp, Bimg);
  k3_tables<<<dim3(LB), dim3(ZB), 0, stream>>>(logZ, lseZ, lpz, lt, ltmz);
  k4_build<<<dim3(TB - 1, BB), dim3(ZB), 0, stream>>>(ng, emb, lt, ltmz, H2);
  k5_forward<<<dim3(BB), dim3(256), 0, stream>>>(Pexp, Bimg, H2, xlen, out);
}

// Round 17
// 412.690 us; speedup vs baseline: 1.4727x; 1.0118x over previous
//
#include <hip/hip_runtime.h>

// HSMM forward, scaled linear recurrence.
// R17 = R16 + distance-4 H prefetch. R16's ~1270 cyc/step vs the ~470-cyc
// structural chain is explained by the distance-2 prefetch: body time floors
// at L3-latency/2 (H2 = 48MB > 32MB L2 aggregate, loads are L3-served).
// Four register buffers h0-h3, period-4 rotation over the 12-body unroll
// (static slots preserved); refill issued in body J lands for body J+4 ->
// coverage 4x body. Math bit-identical to R16 (absmax 0).
// ws: H2 u32[16][512][256][6] (48MiB); part f32[11][64][256]; Bimg bf16 128KB;
//     Pexp f32[256][256]; logZ[11][256]; lseZ[256]; lt[11][256]; ltmz[11][256].

#define VV 50000
#define ZB 256
#define LB 11
#define BB 16
#define TB 512
#define NCHUNK 64
#define CROWS 782  // ceil(VV/NCHUNK)

typedef float v2f __attribute__((ext_vector_type(2)));
typedef float v4f __attribute__((ext_vector_type(4)));
typedef short bs8 __attribute__((ext_vector_type(8)));

static __device__ __forceinline__ float bf16u_to_f(unsigned short u) {
  return __uint_as_float(((unsigned int)u) << 16);
}
static __device__ __forceinline__ unsigned short f_to_bf16u(float f) {
  unsigned int b = __float_as_uint(f);
  b += 0x7FFFu + ((b >> 16) & 1u);
  return (unsigned short)(b >> 16);
}
template <int CTRL>
static __device__ __forceinline__ float dppmax(float x) {
  const int y = __builtin_amdgcn_update_dpp(0, __float_as_int(x), CTRL, 0xF, 0xF, true);
  return fmaxf(x, __int_as_float(y));
}
static __device__ __forceinline__ float rowmax16(float x) {
  x = dppmax<0xB1>(x);   // quad_perm [1,0,3,2]
  x = dppmax<0x4E>(x);   // quad_perm [2,3,0,1]
  x = dppmax<0x124>(x);  // row_ror:4
  x = dppmax<0x128>(x);  // row_ror:8
  return x;
}

#define BAR() do { asm volatile("s_waitcnt lgkmcnt(0)" ::: "memory"); \
                   __builtin_amdgcn_s_barrier();                      \
                   asm volatile("" ::: "memory"); } while (0)

#define HLO(u) __uint_as_float((u) << 16)
#define HHI(u) __uint_as_float((u) & 0xFFFF0000u)

// ---- K1: per-chunk sum of exp(emb) over v (no-max: emb ~ N(0,1), safe in f32)
__global__ void k1_sumexp(const float* __restrict__ emb, float* __restrict__ part) {
  const int l = blockIdx.x / NCHUNK;
  const int c = blockIdx.x % NCHUNK;
  const int t = threadIdx.x;           // 512 threads
  const int zi = (t & 63) * 4;
  const int ro = t >> 6;               // 0..7
  const int v0 = c * CROWS;
  const int v1 = (v0 + CROWS < VV) ? (v0 + CROWS) : VV;
  const float* base = emb + (size_t)l * VV * ZB;
  float a0 = 0.f, a1 = 0.f, a2 = 0.f, a3 = 0.f;
  int v = v0 + ro;
  for (; v + 24 < v1; v += 32) {
    float4 x0 = *(const float4*)(base + (size_t)(v)*ZB + zi);
    float4 x1 = *(const float4*)(base + (size_t)(v + 8) * ZB + zi);
    float4 x2 = *(const float4*)(base + (size_t)(v + 16) * ZB + zi);
    float4 x3 = *(const float4*)(base + (size_t)(v + 24) * ZB + zi);
    a0 += __expf(x0.x) + __expf(x1.x) + __expf(x2.x) + __expf(x3.x);
    a1 += __expf(x0.y) + __expf(x1.y) + __expf(x2.y) + __expf(x3.y);
    a2 += __expf(x0.z) + __expf(x1.z) + __expf(x2.z) + __expf(x3.z);
    a3 += __expf(x0.w) + __expf(x1.w) + __expf(x2.w) + __expf(x3.w);
  }
  for (; v < v1; v += 8) {
    float4 x0 = *(const float4*)(base + (size_t)v * ZB + zi);
    a0 += __expf(x0.x); a1 += __expf(x0.y); a2 += __expf(x0.z); a3 += __expf(x0.w);
  }
  __shared__ float red[8][ZB];
  red[ro][zi] = a0; red[ro][zi + 1] = a1; red[ro][zi + 2] = a2; red[ro][zi + 3] = a3;
  __syncthreads();
  if (t < ZB) {
    float s = 0.f;
#pragma unroll
    for (int r = 0; r < 8; ++r) s += red[r][t];
    part[((size_t)l * NCHUNK + c) * ZB + t] = s;
  }
}

// ---- K2: combine partials -> logZ; lse over l of l_per_z; Pexp rows + Bimg
__global__ void k2_combine(const float* __restrict__ part, const float* __restrict__ zpz,
                           const float* __restrict__ lpz, float* __restrict__ logZ,
                           float* __restrict__ lseZ, float* __restrict__ Pexp,
                           unsigned short* __restrict__ Bimg) {
  const int bid = blockIdx.x;
  const int t = threadIdx.x;  // 256
  if (bid < LB) {
    float s = 0.f;
    for (int c = 0; c < NCHUNK; ++c) s += part[((size_t)bid * NCHUNK + c) * ZB + t];
    logZ[bid * ZB + t] = __logf(s);
  } else if (bid == LB) {
    float lv[LB]; float m = -1e30f;
#pragma unroll
    for (int l = 0; l < LB; ++l) { lv[l] = lpz[t * LB + l]; m = fmaxf(m, lv[l]); }
    float s = 0.f;
#pragma unroll
    for (int l = 0; l < LB; ++l) s += __expf(lv[l] - m);
    lseZ[t] = m + __logf(s);
  } else {
    const int r = bid - (LB + 1);  // z (row of P)
    const float x = zpz[r * ZB + t];
    __shared__ float sA[4], sB[4];
    float m = x;
#pragma unroll
    for (int off = 32; off >= 1; off >>= 1) m = fmaxf(m, __shfl_xor(m, off, 64));
    if ((t & 63) == 0) sA[t >> 6] = m;
    __syncthreads();
    m = fmaxf(fmaxf(sA[0], sA[1]), fmaxf(sA[2], sA[3]));
    const float e = __expf(x - m);
    float s = e;
#pragma unroll
    for (int off = 32; off >= 1; off >>= 1) s += __shfl_xor(s, off, 64);
    if ((t & 63) == 0) sB[t >> 6] = s;
    __syncthreads();
    const float tot = sB[0] + sB[1] + sB[2] + sB[3];
    const float P = e / tot;
    Pexp[r * ZB + t] = P;
    // B-fragment image for k5: frag(tile, slice), lane = g*16 + col, elem = ii
    const int tile = t >> 4, cl = t & 15;
    const int slice = r >> 5, g = (r >> 3) & 3, ii = r & 7;
    Bimg[((size_t)(tile * 8 + slice) * 64 + (g * 16 + cl)) * 8 + ii] = f_to_bf16u(P);
  }
}

// ---- K3: small tables lt = exp(l_term), ltmz = l_term - logZ
__global__ void k3_tables(const float* __restrict__ logZ, const float* __restrict__ lseZ,
                          const float* __restrict__ lpz, float* __restrict__ lt,
                          float* __restrict__ ltmz) {
  const int l = blockIdx.x; const int z = threadIdx.x;
  const float ll = lpz[z * LB + l] - lseZ[z];
  lt[l * ZB + z] = __expf(ll);
  ltmz[l * ZB + z] = ll - logZ[l * ZB + z];
}

// ---- K4: build emissions, ROTATED for fixed slots, pair-packed:
// Hrot[n][z][s] = H_{(n-1-s) mod 12}(n)[z], h[11] == 0.
__global__ void k4_build(const int* __restrict__ ng, const float* __restrict__ emb,
                         const float* __restrict__ lt, const float* __restrict__ ltmz,
                         unsigned int* __restrict__ H2) {
  const int n = blockIdx.x + 1;
  const int b = blockIdx.y;
  const int z = threadIdx.x;  // 256
  float h[12];
#pragma unroll
  for (int l = 0; l < LB; ++l) {
    const int s = n - 1 - l;
    float hv = 0.f;
    if (s >= 0) {
      const int id = ng[((size_t)l * BB + b) * TB + s];
      if (id == 0) hv = lt[l * ZB + z];
      else if (id != 1) hv = __expf(emb[((size_t)l * VV + id) * ZB + z] + ltmz[l * ZB + z]);
    }
    h[l] = hv;
  }
  h[11] = 0.f;
  float hr[12];
#pragma unroll
  for (int s = 0; s < 12; ++s) {
    int idx = (n - 1 - s) % 12; if (idx < 0) idx += 12;
    hr[s] = h[idx];
  }
  unsigned int* dst = H2 + ((size_t)(b * TB + n) * ZB + z) * 6;
#pragma unroll
  for (int i = 0; i < 6; ++i)
    dst[i] = (unsigned int)f_to_bf16u(hr[2 * i]) |
             ((unsigned int)f_to_bf16u(hr[2 * i + 1]) << 16);
}

// ---- K5 body: one scan region; lane owns ONE z (zw).
template <int J>
static __device__ __forceinline__ void body_fn(
    int base, int xl, int lane, int w, int g, int g4, int zw,
    const bs8 (&frag)[4][8], unsigned short (&S_lds)[2][ZB], float (&cells)[4],
    float (&vwin)[12], float& C, float& capS, float& capC,
    uint2 (&hx)[3], const unsigned int*& px) {
  constexpr int WS = J % 12;               // write slot
  constexpr bool RESC = (J % 4) == 0;      // rescale body
  constexpr bool CELLS = (J % 4) == 3;     // cells-write body
  constexpr int RB = J & 1, WB = (J + 1) & 1;
  const int n = base + J;

  float4 cw4 = {0.f, 0.f, 0.f, 0.f};
  if (RESC) cw4 = *(const float4*)cells;   // early LDS issue

  const bs8* ap = (const bs8*)((const char*)S_lds[RB] + g4);
  bs8 ar[8];
#pragma unroll
  for (int s = 0; s < 8; ++s) ar[s] = ap[s * 4];
  v4f aP0 = {0,0,0,0}, aP1 = {0,0,0,0}, aP2 = {0,0,0,0}, aP3 = {0,0,0,0};
  v4f aQ0 = {0,0,0,0}, aQ1 = {0,0,0,0}, aQ2 = {0,0,0,0}, aQ3 = {0,0,0,0};
#pragma unroll
  for (int s = 0; s < 4; ++s) {
    aP0 = __builtin_amdgcn_mfma_f32_16x16x32_bf16(ar[s], frag[0][s], aP0, 0, 0, 0);
    aP1 = __builtin_amdgcn_mfma_f32_16x16x32_bf16(ar[s], frag[1][s], aP1, 0, 0, 0);
    aP2 = __builtin_amdgcn_mfma_f32_16x16x32_bf16(ar[s], frag[2][s], aP2, 0, 0, 0);
    aP3 = __builtin_amdgcn_mfma_f32_16x16x32_bf16(ar[s], frag[3][s], aP3, 0, 0, 0);
    aQ0 = __builtin_amdgcn_mfma_f32_16x16x32_bf16(ar[s + 4], frag[0][s + 4], aQ0, 0, 0, 0);
    aQ1 = __builtin_amdgcn_mfma_f32_16x16x32_bf16(ar[s + 4], frag[1][s + 4], aQ1, 0, 0, 0);
    aQ2 = __builtin_amdgcn_mfma_f32_16x16x32_bf16(ar[s + 4], frag[2][s + 4], aQ2, 0, 0, 0);
    aQ3 = __builtin_amdgcn_mfma_f32_16x16x32_bf16(ar[s + 4], frag[3][s + 4], aQ3, 0, 0, 0);
  }

  // this lane's 6 H-words (read before prefetch overwrites hx)
  const unsigned int wd0 = hx[0].x, wd1 = hx[0].y, wd2 = hx[1].x,
                     wd3 = hx[1].y, wd4 = hx[2].x, wd5 = hx[2].y;

  // partial SDOT over all slots except WS (single z, scalar fma)
  float Sp = 0.f;
#pragma unroll
  for (int s = 0; s < 12; ++s) {
    if (s == WS) continue;
    const int wi = s >> 1;
    const unsigned int wdv = wi == 0 ? wd0 : wi == 1 ? wd1 : wi == 2 ? wd2
                           : wi == 3 ? wd3 : wi == 4 ? wd4 : wd5;
    const float h = (s & 1) ? HHI(wdv) : HLO(wdv);
    Sp = fmaf(h, vwin[s], Sp);
  }
  constexpr int WWI = WS >> 1;
  const unsigned int wdW = WWI == 0 ? wd0 : WWI == 1 ? wd1 : WWI == 2 ? wd2
                         : WWI == 3 ? wd3 : WWI == 4 ? wd4 : wd5;
  const float hWS = (WS & 1) ? HHI(wdW) : HLO(wdW);

  // prefetch Hrot(n+4) into this buffer (consumed by body n+4); 3 uint2
  hx[0] = ((const uint2*)px)[0];
  hx[1] = ((const uint2*)px)[1];
  hx[2] = ((const uint2*)px)[2];
  px += 6144;  // advance 4 time steps (4*256*6 u32)

  // raws for the wave's 4 tiles (replicated across g-groups)
  const float r0 = aP0[0] + aQ0[0];
  const float r1 = aP1[0] + aQ1[0];
  const float r2 = aP2[0] + aQ2[0];
  const float r3 = aP3[0] + aQ3[0];
  const float rsel = (g == 0) ? r0 : (g == 1) ? r1 : (g == 2) ? r2 : r3;

  float S;
  if (RESC) {
    float mx = fmaxf(fmaxf(fmaxf(cw4.x, cw4.y), fmaxf(cw4.z, cw4.w)), 1e-35f);
    const float a = __logf(mx);
    const float es = __expf(-a);
    C += a;
    S = fmaf(hWS, rsel, Sp) * es;
#pragma unroll
    for (int s = 0; s < 12; ++s)
      vwin[s] = ((s == WS) ? rsel : vwin[s]) * es;
  } else {
    S = fmaf(hWS, rsel, Sp);
    vwin[WS] = rsel;
  }
  if (n + 1 == xl) { capS = S; capC = C; }
  S_lds[WB][zw] = f_to_bf16u(S);
  if (CELLS) {
    const float wm = rowmax16(fmaxf(fmaxf(r0, r1), fmaxf(r2, r3)));
    if (lane == 0) cells[w] = wm;
  }
  BAR();
}

// ---- K5: merged single-barrier scan. 256 thr/block (4 waves), 16 blocks.
__global__ __launch_bounds__(256, 1)
void k5_forward(const float* __restrict__ Pexp, const unsigned short* __restrict__ Bimg,
                const unsigned int* __restrict__ H2,
                const int* __restrict__ xlen, float* __restrict__ out) {
  const int b = blockIdx.x;
  const int t = threadIdx.x;
  const int w = t >> 6;
  const int lane = t & 63;
  const int col = lane & 15;
  const int g = lane >> 4;
  const int g4 = g << 4;
  const int zw = w * 16 + col + g * 64;   // the ONE z this lane owns

  __shared__ __align__(16) unsigned short S_lds[2][ZB];
  __shared__ __align__(16) float cells[4];
  __shared__ float redm[4];
  __shared__ float red4[4];

  // resident B = P fragments pinned to AGPRs (4 tiles x 8 slices = 128 AGPR).
  bs8 frag[4][8];
#pragma unroll
  for (int tt = 0; tt < 4; ++tt)
#pragma unroll
    for (int s = 0; s < 8; ++s) {
      frag[tt][s] = *((const bs8*)Bimg + (size_t)((w + 4 * tt) * 8 + s) * 64 + lane);
      asm volatile("" : "+a"(frag[tt][s]));
    }

  const int xl = xlen[b];
  const unsigned int* hb = H2 + (size_t)b * TB * ZB * 6;

  // distance-4 H prefetch ring: h0..h3 hold Hrot(2..5); pointer k advances 4 steps
  uint2 h0[3], h1[3], h2[3], h3[3];
  const unsigned int* p0 = hb + ((size_t)2 * ZB + zw) * 6;
  const unsigned int* p1 = hb + ((size_t)3 * ZB + zw) * 6;
  const unsigned int* p2 = hb + ((size_t)4 * ZB + zw) * 6;
  const unsigned int* p3 = hb + ((size_t)5 * ZB + zw) * 6;
#pragma unroll
  for (int i = 0; i < 3; ++i) {
    h0[i] = ((const uint2*)p0)[i];
    h1[i] = ((const uint2*)p1)[i];
    h2[i] = ((const uint2*)p2)[i];
    h3[i] = ((const uint2*)p3)[i];
  }
  p0 += 6144; p1 += 6144; p2 += 6144; p3 += 6144;  // -> steps 6,7,8,9

  // m0 = max_z P[0][z]  (full 64-lane reduce, then cross-wave)
  const float p = Pexp[zw];
  {
    float pm = p;
#pragma unroll
    for (int off = 32; off >= 1; off >>= 1) pm = fmaxf(pm, __shfl_xor(pm, off, 64));
    if (lane == 0) redm[w] = pm;
  }
  __syncthreads();
  const float m0 = fmaxf(fmaxf(redm[0], redm[1]), fmaxf(redm[2], redm[3]));
  __syncthreads();

  // window slots (common frame), one z per lane
  float vwin[12];
  vwin[0] = p / m0;
#pragma unroll
  for (int s = 1; s < 12; ++s) vwin[s] = 0.f;
  float C = __logf(m0), capC = 0.f, capS = 0.f;

  // S(1) = Hrot(1)[slot 0] * win_0
  {
    const unsigned int u = hb[((size_t)1 * ZB + zw) * 6];
    const float S1 = HLO(u) * vwin[0];
    if (xl == 1) { capS = S1; capC = C; }
    S_lds[1][zw] = f_to_bf16u(S1);
  }
  BAR();

  // bodies needed: n = 1 .. xl-1 (capture at n+1 == xl); xl<=1 handled above.
  const int nb = (xl >= 2) ? (xl - 1) : 0;
  const int kmax = (nb + 11) / 12;

#define BODYARGS xl, lane, w, g, g4, zw, frag, S_lds, cells, vwin, C, capS, capC
#pragma unroll 1
  for (int k = 0; k < kmax; ++k) {
    const int base = 12 * k;
    body_fn<1>(base, BODYARGS, h0, p0);
    body_fn<2>(base, BODYARGS, h1, p1);
    body_fn<3>(base, BODYARGS, h2, p2);
    body_fn<4>(base, BODYARGS, h3, p3);
    body_fn<5>(base, BODYARGS, h0, p0);
    body_fn<6>(base, BODYARGS, h1, p1);
    body_fn<7>(base, BODYARGS, h2, p2);
    body_fn<8>(base, BODYARGS, h3, p3);
    body_fn<9>(base, BODYARGS, h0, p0);
    body_fn<10>(base, BODYARGS, h1, p1);
    body_fn<11>(base, BODYARGS, h2, p2);
    body_fn<12>(base, BODYARGS, h3, p3);
  }
#undef BODYARGS

  // epilogue: out[b] = capC + log(sum_z capS_z); xl==0 -> 0
  {
    float sv = capS;
#pragma unroll
    for (int off = 32; off >= 1; off >>= 1) sv += __shfl_xor(sv, off, 64);
    if (lane == 0) red4[w] = sv;
  }
  __syncthreads();
  if (t == 0) {
    const float tot = red4[0] + red4[1] + red4[2] + red4[3];
    out[b] = (xl == 0) ? 0.f : (__logf(tot) + capC);
  }
}

extern "C" void kernel_launch(void* const* d_in, const int* in_sizes, int n_in,
                              void* d_out, int out_size, void* d_ws, size_t ws_size,
                              hipStream_t stream) {
  (void)in_sizes; (void)n_in; (void)out_size; (void)ws_size;
  const int* xlen = (const int*)d_in[1];
  const int* ng = (const int*)d_in[2];
  const float* emb = (const float*)d_in[3];
  const float* zpz = (const float*)d_in[4];
  const float* lpz = (const float*)d_in[5];
  float* out = (float*)d_out;

  char* ws = (char*)d_ws;
  unsigned int* H2 = (unsigned int*)ws;
  size_t off = (size_t)BB * TB * ZB * 6 * 4;  // 48 MiB
  float* part = (float*)(ws + off); off += (size_t)LB * NCHUNK * ZB * 4;
  unsigned short* Bimg = (unsigned short*)(ws + off); off += (size_t)16 * 8 * 64 * 8 * 2;
  float* Pexp = (float*)(ws + off); off += (size_t)ZB * ZB * 4;
  float* logZ = (float*)(ws + off); off += (size_t)LB * ZB * 4;
  float* lseZ = (float*)(ws + off); off += (size_t)ZB * 4;
  float* lt = (float*)(ws + off); off += (size_t)LB * ZB * 4;
  float* ltmz = (float*)(ws + off); off += (size_t)LB * ZB * 4;

  k1_sumexp<<<dim3(LB * NCHUNK), dim3(512), 0, stream>>>(emb, part);
  k2_combine<<<dim3(LB + 1 + ZB), dim3(ZB), 0, stream>>>(part, zpz, lpz, logZ, lseZ,
                                                         Pexp, Bimg);
  k3_tables<<<dim3(LB), dim3(ZB), 0, stream>>>(logZ, lseZ, lpz, lt, ltmz);
  k4_build<<<dim3(TB - 1, BB), dim3(ZB), 0, stream>>>(ng, emb, lt, ltmz, H2);
  k5_forward<<<dim3(BB), dim3(256), 0, stream>>>(Pexp, Bimg, H2, xlen, out);
}

// Round 19
// 412.373 us; speedup vs baseline: 1.4739x; 1.0008x over previous
//
#include <hip/hip_runtime.h>

// HSMM forward, scaled linear recurrence.
// R19 = R17 with ONE change: the barrier no longer carries a "memory"
// clobber. Theory: asm("s_waitcnt lgkmcnt(0)" ::: "memory") forced the
// compiler to drain vmcnt(0) each step (in-flight C-level H loads must be
// ordered before a memory-clobbering asm) -- exposing one L2/L3 latency per
// step. This explains the R16/R17 1240-cyc step vs ~650 model, the null
// distance-4 result (R17), and the null counted-vmcnt result (R13).
// New BAR: sched_barrier(0) | s_waitcnt lgkmcnt(0) (no clobber) | s_barrier
// | sched_barrier(0). LDS publish/read ordering is held by the side-effecting
// barrier intrinsics; H loads stay in flight with compiler per-use vmcnt.
// Math bit-identical to R17 (absmax 0).
// ws: H2 u32[16][512][256][6] (48MiB); part f32[11][64][256]; Bimg bf16 128KB;
//     Pexp f32[256][256]; logZ[11][256]; lseZ[256]; lt[11][256]; ltmz[11][256].

#define VV 50000
#define ZB 256
#define LB 11
#define BB 16
#define TB 512
#define NCHUNK 64
#define CROWS 782  // ceil(VV/NCHUNK)

typedef float v2f __attribute__((ext_vector_type(2)));
typedef float v4f __attribute__((ext_vector_type(4)));
typedef short bs8 __attribute__((ext_vector_type(8)));

static __device__ __forceinline__ float bf16u_to_f(unsigned short u) {
  return __uint_as_float(((unsigned int)u) << 16);
}
static __device__ __forceinline__ unsigned short f_to_bf16u(float f) {
  unsigned int b = __float_as_uint(f);
  b += 0x7FFFu + ((b >> 16) & 1u);
  return (unsigned short)(b >> 16);
}
template <int CTRL>
static __device__ __forceinline__ float dppmax(float x) {
  const int y = __builtin_amdgcn_update_dpp(0, __float_as_int(x), CTRL, 0xF, 0xF, true);
  return fmaxf(x, __int_as_float(y));
}
static __device__ __forceinline__ float rowmax16(float x) {
  x = dppmax<0xB1>(x);   // quad_perm [1,0,3,2]
  x = dppmax<0x4E>(x);   // quad_perm [2,3,0,1]
  x = dppmax<0x124>(x);  // row_ror:4
  x = dppmax<0x128>(x);  // row_ror:8
  return x;
}

// Raw barrier: NO memory clobber (keeps H global loads in flight across the
// barrier). sched_barrier(0) pins LDS publish/read ordering at both IR and
// MI level; lgkmcnt(0) guarantees the ds_write landed before s_barrier.
#define BAR() do { __builtin_amdgcn_sched_barrier(0);          \
                   asm volatile("s_waitcnt lgkmcnt(0)");       \
                   __builtin_amdgcn_s_barrier();               \
                   __builtin_amdgcn_sched_barrier(0); } while (0)

#define HLO(u) __uint_as_float((u) << 16)
#define HHI(u) __uint_as_float((u) & 0xFFFF0000u)

// ---- K1: per-chunk sum of exp(emb) over v (no-max: emb ~ N(0,1), safe in f32)
__global__ void k1_sumexp(const float* __restrict__ emb, float* __restrict__ part) {
  const int l = blockIdx.x / NCHUNK;
  const int c = blockIdx.x % NCHUNK;
  const int t = threadIdx.x;           // 512 threads
  const int zi = (t & 63) * 4;
  const int ro = t >> 6;               // 0..7
  const int v0 = c * CROWS;
  const int v1 = (v0 + CROWS < VV) ? (v0 + CROWS) : VV;
  const float* base = emb + (size_t)l * VV * ZB;
  float a0 = 0.f, a1 = 0.f, a2 = 0.f, a3 = 0.f;
  int v = v0 + ro;
  for (; v + 24 < v1; v += 32) {
    float4 x0 = *(const float4*)(base + (size_t)(v)*ZB + zi);
    float4 x1 = *(const float4*)(base + (size_t)(v + 8) * ZB + zi);
    float4 x2 = *(const float4*)(base + (size_t)(v + 16) * ZB + zi);
    float4 x3 = *(const float4*)(base + (size_t)(v + 24) * ZB + zi);
    a0 += __expf(x0.x) + __expf(x1.x) + __expf(x2.x) + __expf(x3.x);
    a1 += __expf(x0.y) + __expf(x1.y) + __expf(x2.y) + __expf(x3.y);
    a2 += __expf(x0.z) + __expf(x1.z) + __expf(x2.z) + __expf(x3.z);
    a3 += __expf(x0.w) + __expf(x1.w) + __expf(x2.w) + __expf(x3.w);
  }
  for (; v < v1; v += 8) {
    float4 x0 = *(const float4*)(base + (size_t)v * ZB + zi);
    a0 += __expf(x0.x); a1 += __expf(x0.y); a2 += __expf(x0.z); a3 += __expf(x0.w);
  }
  __shared__ float red[8][ZB];
  red[ro][zi] = a0; red[ro][zi + 1] = a1; red[ro][zi + 2] = a2; red[ro][zi + 3] = a3;
  __syncthreads();
  if (t < ZB) {
    float s = 0.f;
#pragma unroll
    for (int r = 0; r < 8; ++r) s += red[r][t];
    part[((size_t)l * NCHUNK + c) * ZB + t] = s;
  }
}

// ---- K2: combine partials -> logZ; lse over l of l_per_z; Pexp rows + Bimg
__global__ void k2_combine(const float* __restrict__ part, const float* __restrict__ zpz,
                           const float* __restrict__ lpz, float* __restrict__ logZ,
                           float* __restrict__ lseZ, float* __restrict__ Pexp,
                           unsigned short* __restrict__ Bimg) {
  const int bid = blockIdx.x;
  const int t = threadIdx.x;  // 256
  if (bid < LB) {
    float s = 0.f;
    for (int c = 0; c < NCHUNK; ++c) s += part[((size_t)bid * NCHUNK + c) * ZB + t];
    logZ[bid * ZB + t] = __logf(s);
  } else if (bid == LB) {
    float lv[LB]; float m = -1e30f;
#pragma unroll
    for (int l = 0; l < LB; ++l) { lv[l] = lpz[t * LB + l]; m = fmaxf(m, lv[l]); }
    float s = 0.f;
#pragma unroll
    for (int l = 0; l < LB; ++l) s += __expf(lv[l] - m);
    lseZ[t] = m + __logf(s);
  } else {
    const int r = bid - (LB + 1);  // z (row of P)
    const float x = zpz[r * ZB + t];
    __shared__ float sA[4], sB[4];
    float m = x;
#pragma unroll
    for (int off = 32; off >= 1; off >>= 1) m = fmaxf(m, __shfl_xor(m, off, 64));
    if ((t & 63) == 0) sA[t >> 6] = m;
    __syncthreads();
    m = fmaxf(fmaxf(sA[0], sA[1]), fmaxf(sA[2], sA[3]));
    const float e = __expf(x - m);
    float s = e;
#pragma unroll
    for (int off = 32; off >= 1; off >>= 1) s += __shfl_xor(s, off, 64);
    if ((t & 63) == 0) sB[t >> 6] = s;
    __syncthreads();
    const float tot = sB[0] + sB[1] + sB[2] + sB[3];
    const float P = e / tot;
    Pexp[r * ZB + t] = P;
    // B-fragment image for k5: frag(tile, slice), lane = g*16 + col, elem = ii
    const int tile = t >> 4, cl = t & 15;
    const int slice = r >> 5, g = (r >> 3) & 3, ii = r & 7;
    Bimg[((size_t)(tile * 8 + slice) * 64 + (g * 16 + cl)) * 8 + ii] = f_to_bf16u(P);
  }
}

// ---- K3: small tables lt = exp(l_term), ltmz = l_term - logZ
__global__ void k3_tables(const float* __restrict__ logZ, const float* __restrict__ lseZ,
                          const float* __restrict__ lpz, float* __restrict__ lt,
                          float* __restrict__ ltmz) {
  const int l = blockIdx.x; const int z = threadIdx.x;
  const float ll = lpz[z * LB + l] - lseZ[z];
  lt[l * ZB + z] = __expf(ll);
  ltmz[l * ZB + z] = ll - logZ[l * ZB + z];
}

// ---- K4: build emissions, ROTATED for fixed slots, pair-packed:
// Hrot[n][z][s] = H_{(n-1-s) mod 12}(n)[z], h[11] == 0.
__global__ void k4_build(const int* __restrict__ ng, const float* __restrict__ emb,
                         const float* __restrict__ lt, const float* __restrict__ ltmz,
                         unsigned int* __restrict__ H2) {
  const int n = blockIdx.x + 1;
  const int b = blockIdx.y;
  const int z = threadIdx.x;  // 256
  float h[12];
#pragma unroll
  for (int l = 0; l < LB; ++l) {
    const int s = n - 1 - l;
    float hv = 0.f;
    if (s >= 0) {
      const int id = ng[((size_t)l * BB + b) * TB + s];
      if (id == 0) hv = lt[l * ZB + z];
      else if (id != 1) hv = __expf(emb[((size_t)l * VV + id) * ZB + z] + ltmz[l * ZB + z]);
    }
    h[l] = hv;
  }
  h[11] = 0.f;
  float hr[12];
#pragma unroll
  for (int s = 0; s < 12; ++s) {
    int idx = (n - 1 - s) % 12; if (idx < 0) idx += 12;
    hr[s] = h[idx];
  }
  unsigned int* dst = H2 + ((size_t)(b * TB + n) * ZB + z) * 6;
#pragma unroll
  for (int i = 0; i < 6; ++i)
    dst[i] = (unsigned int)f_to_bf16u(hr[2 * i]) |
             ((unsigned int)f_to_bf16u(hr[2 * i + 1]) << 16);
}

// ---- K5 body: one scan region; lane owns ONE z (zw).
template <int J>
static __device__ __forceinline__ void body_fn(
    int base, int xl, int lane, int w, int g, int g4, int zw,
    const bs8 (&frag)[4][8], unsigned short (&S_lds)[2][ZB], float (&cells)[4],
    float (&vwin)[12], float& C, float& capS, float& capC,
    uint2 (&hx)[3], const unsigned int*& px) {
  constexpr int WS = J % 12;               // write slot
  constexpr bool RESC = (J % 4) == 0;      // rescale body
  constexpr bool CELLS = (J % 4) == 3;     // cells-write body
  constexpr int RB = J & 1, WB = (J + 1) & 1;
  const int n = base + J;

  float4 cw4 = {0.f, 0.f, 0.f, 0.f};
  if (RESC) cw4 = *(const float4*)cells;   // early LDS issue

  const bs8* ap = (const bs8*)((const char*)S_lds[RB] + g4);
  bs8 ar[8];
#pragma unroll
  for (int s = 0; s < 8; ++s) ar[s] = ap[s * 4];
  v4f aP0 = {0,0,0,0}, aP1 = {0,0,0,0}, aP2 = {0,0,0,0}, aP3 = {0,0,0,0};
  v4f aQ0 = {0,0,0,0}, aQ1 = {0,0,0,0}, aQ2 = {0,0,0,0}, aQ3 = {0,0,0,0};
#pragma unroll
  for (int s = 0; s < 4; ++s) {
    aP0 = __builtin_amdgcn_mfma_f32_16x16x32_bf16(ar[s], frag[0][s], aP0, 0, 0, 0);
    aP1 = __builtin_amdgcn_mfma_f32_16x16x32_bf16(ar[s], frag[1][s], aP1, 0, 0, 0);
    aP2 = __builtin_amdgcn_mfma_f32_16x16x32_bf16(ar[s], frag[2][s], aP2, 0, 0, 0);
    aP3 = __builtin_amdgcn_mfma_f32_16x16x32_bf16(ar[s], frag[3][s], aP3, 0, 0, 0);
    aQ0 = __builtin_amdgcn_mfma_f32_16x16x32_bf16(ar[s + 4], frag[0][s + 4], aQ0, 0, 0, 0);
    aQ1 = __builtin_amdgcn_mfma_f32_16x16x32_bf16(ar[s + 4], frag[1][s + 4], aQ1, 0, 0, 0);
    aQ2 = __builtin_amdgcn_mfma_f32_16x16x32_bf16(ar[s + 4], frag[2][s + 4], aQ2, 0, 0, 0);
    aQ3 = __builtin_amdgcn_mfma_f32_16x16x32_bf16(ar[s + 4], frag[3][s + 4], aQ3, 0, 0, 0);
  }

  // this lane's 6 H-words (read before prefetch overwrites hx)
  const unsigned int wd0 = hx[0].x, wd1 = hx[0].y, wd2 = hx[1].x,
                     wd3 = hx[1].y, wd4 = hx[2].x, wd5 = hx[2].y;

  // partial SDOT over all slots except WS (single z, scalar fma)
  float Sp = 0.f;
#pragma unroll
  for (int s = 0; s < 12; ++s) {
    if (s == WS) continue;
    const int wi = s >> 1;
    const unsigned int wdv = wi == 0 ? wd0 : wi == 1 ? wd1 : wi == 2 ? wd2
                           : wi == 3 ? wd3 : wi == 4 ? wd4 : wd5;
    const float h = (s & 1) ? HHI(wdv) : HLO(wdv);
    Sp = fmaf(h, vwin[s], Sp);
  }
  constexpr int WWI = WS >> 1;
  const unsigned int wdW = WWI == 0 ? wd0 : WWI == 1 ? wd1 : WWI == 2 ? wd2
                         : WWI == 3 ? wd3 : WWI == 4 ? wd4 : wd5;
  const float hWS = (WS & 1) ? HHI(wdW) : HLO(wdW);

  // prefetch Hrot(n+4) into this buffer (consumed by body n+4); 3 uint2
  hx[0] = ((const uint2*)px)[0];
  hx[1] = ((const uint2*)px)[1];
  hx[2] = ((const uint2*)px)[2];
  px += 6144;  // advance 4 time steps (4*256*6 u32)

  // raws for the wave's 4 tiles (replicated across g-groups)
  const float r0 = aP0[0] + aQ0[0];
  const float r1 = aP1[0] + aQ1[0];
  const float r2 = aP2[0] + aQ2[0];
  const float r3 = aP3[0] + aQ3[0];
  const float rsel = (g == 0) ? r0 : (g == 1) ? r1 : (g == 2) ? r2 : r3;

  float S;
  if (RESC) {
    float mx = fmaxf(fmaxf(fmaxf(cw4.x, cw4.y), fmaxf(cw4.z, cw4.w)), 1e-35f);
    const float a = __logf(mx);
    const float es = __expf(-a);
    C += a;
    S = fmaf(hWS, rsel, Sp) * es;
#pragma unroll
    for (int s = 0; s < 12; ++s)
      vwin[s] = ((s == WS) ? rsel : vwin[s]) * es;
  } else {
    S = fmaf(hWS, rsel, Sp);
    vwin[WS] = rsel;
  }
  if (n + 1 == xl) { capS = S; capC = C; }
  S_lds[WB][zw] = f_to_bf16u(S);
  if (CELLS) {
    const float wm = rowmax16(fmaxf(fmaxf(r0, r1), fmaxf(r2, r3)));
    if (lane == 0) cells[w] = wm;
  }
  BAR();
}

// ---- K5: merged single-barrier scan. 256 thr/block (4 waves), 16 blocks.
__global__ __launch_bounds__(256, 1)
void k5_forward(const float* __restrict__ Pexp, const unsigned short* __restrict__ Bimg,
                const unsigned int* __restrict__ H2,
                const int* __restrict__ xlen, float* __restrict__ out) {
  const int b = blockIdx.x;
  const int t = threadIdx.x;
  const int w = t >> 6;
  const int lane = t & 63;
  const int col = lane & 15;
  const int g = lane >> 4;
  const int g4 = g << 4;
  const int zw = w * 16 + col + g * 64;   // the ONE z this lane owns

  __shared__ __align__(16) unsigned short S_lds[2][ZB];
  __shared__ __align__(16) float cells[4];
  __shared__ float redm[4];
  __shared__ float red4[4];

  // resident B = P fragments pinned to AGPRs (4 tiles x 8 slices = 128 AGPR).
  bs8 frag[4][8];
#pragma unroll
  for (int tt = 0; tt < 4; ++tt)
#pragma unroll
    for (int s = 0; s < 8; ++s) {
      frag[tt][s] = *((const bs8*)Bimg + (size_t)((w + 4 * tt) * 8 + s) * 64 + lane);
      asm volatile("" : "+a"(frag[tt][s]));
    }

  const int xl = xlen[b];
  const unsigned int* hb = H2 + (size_t)b * TB * ZB * 6;

  // distance-4 H prefetch ring: h0..h3 hold Hrot(2..5); pointer advances 4 steps
  uint2 h0[3], h1[3], h2[3], h3[3];
  const unsigned int* p0 = hb + ((size_t)2 * ZB + zw) * 6;
  const unsigned int* p1 = hb + ((size_t)3 * ZB + zw) * 6;
  const unsigned int* p2 = hb + ((size_t)4 * ZB + zw) * 6;
  const unsigned int* p3 = hb + ((size_t)5 * ZB + zw) * 6;
#pragma unroll
  for (int i = 0; i < 3; ++i) {
    h0[i] = ((const uint2*)p0)[i];
    h1[i] = ((const uint2*)p1)[i];
    h2[i] = ((const uint2*)p2)[i];
    h3[i] = ((const uint2*)p3)[i];
  }
  p0 += 6144; p1 += 6144; p2 += 6144; p3 += 6144;  // -> steps 6,7,8,9

  // m0 = max_z P[0][z]  (full 64-lane reduce, then cross-wave)
  const float p = Pexp[zw];
  {
    float pm = p;
#pragma unroll
    for (int off = 32; off >= 1; off >>= 1) pm = fmaxf(pm, __shfl_xor(pm, off, 64));
    if (lane == 0) redm[w] = pm;
  }
  __syncthreads();
  const float m0 = fmaxf(fmaxf(redm[0], redm[1]), fmaxf(redm[2], redm[3]));
  __syncthreads();

  // window slots (common frame), one z per lane
  float vwin[12];
  vwin[0] = p / m0;
#pragma unroll
  for (int s = 1; s < 12; ++s) vwin[s] = 0.f;
  float C = __logf(m0), capC = 0.f, capS = 0.f;

  // S(1) = Hrot(1)[slot 0] * win_0
  {
    const unsigned int u = hb[((size_t)1 * ZB + zw) * 6];
    const float S1 = HLO(u) * vwin[0];
    if (xl == 1) { capS = S1; capC = C; }
    S_lds[1][zw] = f_to_bf16u(S1);
  }
  if (t == 0) cells[0] = 0.f;  // never read before first CELLS write? (J=3 writes,
                               // J=4 reads) -- initialized for safety.
  BAR();

  // bodies needed: n = 1 .. xl-1 (capture at n+1 == xl); xl<=1 handled above.
  const int nb = (xl >= 2) ? (xl - 1) : 0;
  const int kmax = (nb + 11) / 12;

#define BODYARGS xl, lane, w, g, g4, zw, frag, S_lds, cells, vwin, C, capS, capC
#pragma unroll 1
  for (int k = 0; k < kmax; ++k) {
    const int base = 12 * k;
    body_fn<1>(base, BODYARGS, h0, p0);
    body_fn<2>(base, BODYARGS, h1, p1);
    body_fn<3>(base, BODYARGS, h2, p2);
    body_fn<4>(base, BODYARGS, h3, p3);
    body_fn<5>(base, BODYARGS, h0, p0);
    body_fn<6>(base, BODYARGS, h1, p1);
    body_fn<7>(base, BODYARGS, h2, p2);
    body_fn<8>(base, BODYARGS, h3, p3);
    body_fn<9>(base, BODYARGS, h0, p0);
    body_fn<10>(base, BODYARGS, h1, p1);
    body_fn<11>(base, BODYARGS, h2, p2);
    body_fn<12>(base, BODYARGS, h3, p3);
  }
#undef BODYARGS

  // epilogue: out[b] = capC + log(sum_z capS_z); xl==0 -> 0
  {
    float sv = capS;
#pragma unroll
    for (int off = 32; off >= 1; off >>= 1) sv += __shfl_xor(sv, off, 64);
    if (lane == 0) red4[w] = sv;
  }
  __syncthreads();
  if (t == 0) {
    const float tot = red4[0] + red4[1] + red4[2] + red4[3];
    out[b] = (xl == 0) ? 0.f : (__logf(tot) + capC);
  }
}

extern "C" void kernel_launch(void* const* d_in, const int* in_sizes, int n_in,
                              void* d_out, int out_size, void* d_ws, size_t ws_size,
                              hipStream_t stream) {
  (void)in_sizes; (void)n_in; (void)out_size; (void)ws_size;
  const int* xlen = (const int*)d_in[1];
  const int* ng = (const int*)d_in[2];
  const float* emb = (const float*)d_in[3];
  const float* zpz = (const float*)d_in[4];
  const float* lpz = (const float*)d_in[5];
  float* out = (float*)d_out;

  char* ws = (char*)d_ws;
  unsigned int* H2 = (unsigned int*)ws;
  size_t off = (size_t)BB * TB * ZB * 6 * 4;  // 48 MiB
  float* part = (float*)(ws + off); off += (size_t)LB * NCHUNK * ZB * 4;
  unsigned short* Bimg = (unsigned short*)(ws + off); off += (size_t)16 * 8 * 64 * 8 * 2;
  float* Pexp = (float*)(ws + off); off += (size_t)ZB * ZB * 4;
  float* logZ = (float*)(ws + off); off += (size_t)LB * ZB * 4;
  float* lseZ = (float*)(ws + off); off += (size_t)ZB * 4;
  float* lt = (float*)(ws + off); off += (size_t)LB * ZB * 4;
  float* ltmz = (float*)(ws + off); off += (size_t)LB * ZB * 4;

  k1_sumexp<<<dim3(LB * NCHUNK), dim3(512), 0, stream>>>(emb, part);
  k2_combine<<<dim3(LB + 1 + ZB), dim3(ZB), 0, stream>>>(part, zpz, lpz, logZ, lseZ,
                                                         Pexp, Bimg);
  k3_tables<<<dim3(LB), dim3(ZB), 0, stream>>>(logZ, lseZ, lpz, lt, ltmz);
  k4_build<<<dim3(TB - 1, BB), dim3(ZB), 0, stream>>>(ng, emb, lt, ltmz, H2);
  k5_forward<<<dim3(BB), dim3(256), 0, stream>>>(Pexp, Bimg, H2, xlen, out);
}